// Round 17
// baseline (441.290 us; speedup 1.0000x reference)
//
#include <hip/hip_runtime.h>
#include <hip/hip_bf16.h>
#include <hip/hip_fp16.h>
#include <math.h>

#define SEQ 2048
#define DMODEL 1024
#define NH 16
#define DHEAD 64
#define FFDIM 4096
#define NPOSE 128
#define MLPWID 32
#define EPSV 1e-5f
#define CHUNK 1024
#define NCH (SEQ / CHUNK)

typedef unsigned short ushort_t;
typedef unsigned int uint_t;
typedef _Float16 f16;
typedef __attribute__((ext_vector_type(8))) _Float16 f16x8;
typedef __attribute__((ext_vector_type(4))) float f32x4;

union HF8 { f16x8 v; f16 h[8]; ushort_t s[8]; uint2 u2[2]; uint4 u4; };
union U1H2 { uint_t u; f16 h[2]; };
union U2H4 { uint2 u; f16 h[4]; };

__device__ __forceinline__ float sigm(float x) {
    return __builtin_amdgcn_rcpf(1.0f + __expf(-x));
}
__device__ __forceinline__ void gl_lds16(const void* g, void* l) {
    __builtin_amdgcn_global_load_lds((const __attribute__((address_space(1))) uint_t*)g,
                                     (__attribute__((address_space(3))) uint_t*)l, 16, 0, 0);
}

// ---------------- RMSNorm, f16 out ----------------
__global__ __launch_bounds__(256) void rmsnormf_k(const float* __restrict__ x,
                                                  const float* __restrict__ w,
                                                  f16* __restrict__ o) {
    int row = blockIdx.x;
    int tid = threadIdx.x;
    const float4* xr = (const float4*)(x + (size_t)row * DMODEL);
    float4 v = xr[tid];
    float ss = v.x * v.x + v.y * v.y + v.z * v.z + v.w * v.w;
#pragma unroll
    for (int d = 1; d < 64; d <<= 1) ss += __shfl_xor(ss, d, 64);
    __shared__ float red[4];
    int lane = tid & 63, wv = tid >> 6;
    if (lane == 0) red[wv] = ss;
    __syncthreads();
    float tot = red[0] + red[1] + red[2] + red[3];
    float r = rsqrtf(tot / (float)DMODEL + EPSV);
    const float4* wr = (const float4*)w;
    float4 wv4 = wr[tid];
    U2H4 ob;
    ob.h[0] = (f16)(v.x * r * wv4.x);
    ob.h[1] = (f16)(v.y * r * wv4.y);
    ob.h[2] = (f16)(v.z * r * wv4.z);
    ob.h[3] = (f16)(v.w * r * wv4.w);
    ((uint2*)(o + (size_t)row * DMODEL))[tid] = ob.u;
}

// ---------------- V transpose ----------------
__global__ __launch_bounds__(256) void tv_k(const ushort_t* __restrict__ vb,
                                            ushort_t* __restrict__ vt) {
    int h = blockIdx.y, t0 = blockIdx.x * 64;
    __shared__ ushort_t T[64][76];
    int tid = threadIdx.x;
#pragma unroll
    for (int it = 0; it < 2; it++) {
        int a = tid + it * 256;
        int t = a >> 3, c8 = (a & 7) * 8;
        HF8 v;
        v.u4 = *(const uint4*)(vb + (size_t)(t0 + t) * DMODEL + h * 64 + c8);
#pragma unroll
        for (int j = 0; j < 8; j++) T[c8 + j][t] = v.s[j];
    }
    __syncthreads();
#pragma unroll
    for (int it = 0; it < 2; it++) {
        int a = tid + it * 256;
        int d = a >> 3, c8 = (a & 7) * 8;
        HF8 o;
#pragma unroll
        for (int j = 0; j < 8; j++) o.s[j] = T[d][c8 + j];
        *(uint4*)(vt + ((size_t)h * 64 + d) * SEQ + t0 + c8) = o.u4;
    }
}

// ---------------- weight transpose+convert: f32[K][N] -> f16[N][K] ----------------
__global__ __launch_bounds__(256) void transconv_k(const float* __restrict__ in,
                                                   f16* __restrict__ out,
                                                   int K, int N) {
    __shared__ f16 T[64][72];
    int k0 = blockIdx.y * 64, n0 = blockIdx.x * 64;
    int tid = threadIdx.x;
    int r = tid >> 4, c4 = (tid & 15) * 4;
#pragma unroll
    for (int i = 0; i < 4; i++) {
        float4 v = *(const float4*)(in + (size_t)(k0 + r + i * 16) * N + n0 + c4);
        T[c4 + 0][r + i * 16] = (f16)v.x;
        T[c4 + 1][r + i * 16] = (f16)v.y;
        T[c4 + 2][r + i * 16] = (f16)v.z;
        T[c4 + 3][r + i * 16] = (f16)v.w;
    }
    __syncthreads();
    int n = tid >> 2, kk = (tid & 3) * 16;
    uint4* dst = (uint4*)(out + (size_t)(n0 + n) * K + k0 + kk);
    dst[0] = *(const uint4*)&T[n][kk];
    dst[1] = *(const uint4*)&T[n][kk + 8];
}

// ---------------- 3-way weight transpose (QKV) via blockIdx.z ----------------
__global__ __launch_bounds__(256) void transconv3_k(const float* __restrict__ w0,
                                                    const float* __restrict__ w1p,
                                                    const float* __restrict__ w2p,
                                                    f16* __restrict__ out) {
    const int K = DMODEL, N = DMODEL;
    const float* in = (blockIdx.z == 0) ? w0 : (blockIdx.z == 1) ? w1p : w2p;
    f16* o = out + (size_t)blockIdx.z * DMODEL * DMODEL;
    __shared__ f16 T[64][72];
    int k0 = blockIdx.y * 64, n0 = blockIdx.x * 64;
    int tid = threadIdx.x;
    int r = tid >> 4, c4 = (tid & 15) * 4;
#pragma unroll
    for (int i = 0; i < 4; i++) {
        float4 v = *(const float4*)(in + (size_t)(k0 + r + i * 16) * N + n0 + c4);
        T[c4 + 0][r + i * 16] = (f16)v.x;
        T[c4 + 1][r + i * 16] = (f16)v.y;
        T[c4 + 2][r + i * 16] = (f16)v.z;
        T[c4 + 3][r + i * 16] = (f16)v.w;
    }
    __syncthreads();
    int n = tid >> 2, kk = (tid & 3) * 16;
    uint4* dst = (uint4*)(o + (size_t)(n0 + n) * K + k0 + kk);
    dst[0] = *(const uint4*)&T[n][kk];
    dst[1] = *(const uint4*)&T[n][kk + 8];
}

// ---------------- w1/w3 transpose+convert, row-interleaved ----------------
__global__ __launch_bounds__(256) void transconv2_k(const float* __restrict__ w1,
                                                    const float* __restrict__ w3,
                                                    f16* __restrict__ out,
                                                    int K, int N) {
    __shared__ f16 T[64][72];
    int k0 = blockIdx.y * 64, n0 = blockIdx.x * 64;
    int tid = threadIdx.x;
    int r = tid >> 4, c4 = (tid & 15) * 4;
    int n = tid >> 2, kk = (tid & 3) * 16;
#pragma unroll
    for (int half = 0; half < 2; half++) {
        const float* in = half ? w3 : w1;
#pragma unroll
        for (int i = 0; i < 4; i++) {
            float4 v = *(const float4*)(in + (size_t)(k0 + r + i * 16) * N + n0 + c4);
            T[c4 + 0][r + i * 16] = (f16)v.x;
            T[c4 + 1][r + i * 16] = (f16)v.y;
            T[c4 + 2][r + i * 16] = (f16)v.z;
            T[c4 + 3][r + i * 16] = (f16)v.w;
        }
        __syncthreads();
        int gc = n0 + n;
        int rp = (gc >> 4) * 32 + (gc & 15) + half * 16;
        uint4* dst = (uint4*)(out + (size_t)rp * K + k0 + kk);
        dst[0] = *(const uint4*)&T[n][kk];
        dst[1] = *(const uint4*)&T[n][kk + 8];
        __syncthreads();
    }
}

// ---------------- f16 MFMA GEMM 128x128 (TN), XCD-swizzled ----------------
// mode 0: f32 out (+add). mode 1: f16 out. mode 4: w1w3-interleaved silu-mul.
__global__ __launch_bounds__(256) void gemm128_k(const f16* __restrict__ A,
                                                 const f16* __restrict__ Bt,
                                                 const float* __restrict__ add,
                                                 void* __restrict__ Cout,
                                                 int M, int N, int K, int mode) {
    __shared__ f16 Al[128 * 32];
    __shared__ f16 Bl[128 * 32];
    int tid = threadIdx.x;
    int lane = tid & 63, wave = tid >> 6;
    int gx = gridDim.x, gy = gridDim.y;
    int nwg = gx * gy;
    int bx = blockIdx.x, by = blockIdx.y;
    if ((nwg & 7) == 0) {
        int flat = by * gx + bx;
        int cpx = nwg >> 3;
        int l = (flat & 7) * cpx + (flat >> 3);
        bx = l / gy;
        by = l % gy;
    }
    int brow = by * 128, bcol = bx * 128;
    int wr = (wave >> 1) * 64, wc = (wave & 1) * 64;
    f32x4 acc[4][4];
#pragma unroll
    for (int m = 0; m < 4; m++)
#pragma unroll
        for (int n = 0; n < 4; n++) acc[m][n] = (f32x4){0.f, 0.f, 0.f, 0.f};

    const f16* Ag = A + (size_t)(brow + (tid >> 2)) * K + (tid & 3) * 8;
    const f16* Bg = Bt + (size_t)(bcol + (tid >> 2)) * K + (tid & 3) * 8;
    f16* Ald = &Al[wave * 512];
    f16* Bld = &Bl[wave * 512];
    size_t rstep = (size_t)64 * K;

    for (int k0 = 0; k0 < K; k0 += 32) {
        gl_lds16(Ag + k0, Ald);
        gl_lds16(Ag + k0 + rstep, Ald + 2048);
        gl_lds16(Bg + k0, Bld);
        gl_lds16(Bg + k0 + rstep, Bld + 2048);
        __syncthreads();
        f16x8 af[4], bfr[4];
        int arow = wr + (lane & 15);
        int brw = wc + (lane & 15);
        int kof = (lane >> 4) * 8;
#pragma unroll
        for (int m = 0; m < 4; m++) af[m] = *(const f16x8*)&Al[(arow + m * 16) * 32 + kof];
#pragma unroll
        for (int n = 0; n < 4; n++) bfr[n] = *(const f16x8*)&Bl[(brw + n * 16) * 32 + kof];
#pragma unroll
        for (int m = 0; m < 4; m++)
#pragma unroll
            for (int n = 0; n < 4; n++)
                acc[m][n] = __builtin_amdgcn_mfma_f32_16x16x32_f16(af[m], bfr[n], acc[m][n], 0, 0, 0);
        __syncthreads();
    }
    int crow0 = brow + wr + (lane >> 4) * 4;
    int ccol = bcol + wc + (lane & 15);
#pragma unroll
    for (int m = 0; m < 4; m++)
#pragma unroll
        for (int j = 0; j < 4; j++) {
            int row = crow0 + m * 16 + j;
            if (mode == 4) {
#pragma unroll
                for (int n = 0; n < 4; n += 2) {
                    int c = ccol + n * 16;
                    int colOut = (c >> 5) * 16 + (c & 15);
                    float v1 = acc[m][n][j];
                    float v3 = acc[m][n + 1][j];
                    ((f16*)Cout)[(size_t)row * (N / 2) + colOut] =
                        (f16)(v1 * sigm(v1) * v3);
                }
            } else {
#pragma unroll
                for (int n = 0; n < 4; n++) {
                    int col = ccol + n * 16;
                    float v = acc[m][n][j];
                    if (mode == 0) {
                        if (add) v += add[(size_t)row * N + col];
                        ((float*)Cout)[(size_t)row * N + col] = v;
                    } else {
                        ((f16*)Cout)[(size_t)row * N + col] = (f16)v;
                    }
                }
            }
        }
}

// ---------------- f16 MFMA GEMM 64x64 (TN), XCD-swizzled ----------------
// mode 0: f32 out (+add). mode 1: f16. mode 2: qkv split (Cout=q, p2=k, p3=v).
__global__ __launch_bounds__(256) void gemm64_k(const f16* __restrict__ A,
                                                const f16* __restrict__ Bt,
                                                const float* __restrict__ add,
                                                void* __restrict__ Cout,
                                                int M, int N, int K, int mode,
                                                f16* __restrict__ p2,
                                                f16* __restrict__ p3) {
    __shared__ f16 Al[64 * 32];
    __shared__ f16 Bl[64 * 32];
    int tid = threadIdx.x;
    int lane = tid & 63, wave = tid >> 6;
    int gx = gridDim.x, gy = gridDim.y;
    int nwg = gx * gy;
    int bx = blockIdx.x, by = blockIdx.y;
    if ((nwg & 7) == 0) {
        int flat = by * gx + bx;
        int cpx = nwg >> 3;
        int l = (flat & 7) * cpx + (flat >> 3);
        bx = l / gy;
        by = l % gy;
    }
    int brow = by * 64, bcol = bx * 64;
    int wr = (wave >> 1) * 32, wc = (wave & 1) * 32;
    f32x4 acc[2][2];
#pragma unroll
    for (int m = 0; m < 2; m++)
#pragma unroll
        for (int n = 0; n < 2; n++) acc[m][n] = (f32x4){0.f, 0.f, 0.f, 0.f};

    const f16* Ag = A + (size_t)(brow + (tid >> 2)) * K + (tid & 3) * 8;
    const f16* Bg = Bt + (size_t)(bcol + (tid >> 2)) * K + (tid & 3) * 8;
    f16* Ald = &Al[wave * 512];
    f16* Bld = &Bl[wave * 512];

    for (int k0 = 0; k0 < K; k0 += 32) {
        gl_lds16(Ag + k0, Ald);
        gl_lds16(Bg + k0, Bld);
        __syncthreads();
        f16x8 af[2], bfr[2];
        int kof = (lane >> 4) * 8;
#pragma unroll
        for (int m = 0; m < 2; m++)
            af[m] = *(const f16x8*)&Al[(wr + m * 16 + (lane & 15)) * 32 + kof];
#pragma unroll
        for (int n = 0; n < 2; n++)
            bfr[n] = *(const f16x8*)&Bl[(wc + n * 16 + (lane & 15)) * 32 + kof];
#pragma unroll
        for (int m = 0; m < 2; m++)
#pragma unroll
            for (int n = 0; n < 2; n++)
                acc[m][n] = __builtin_amdgcn_mfma_f32_16x16x32_f16(af[m], bfr[n], acc[m][n], 0, 0, 0);
        __syncthreads();
    }
    int crow0 = brow + wr + (lane >> 4) * 4;
    int ccol = bcol + wc + (lane & 15);
#pragma unroll
    for (int m = 0; m < 2; m++)
#pragma unroll
        for (int j = 0; j < 4; j++) {
            int row = crow0 + m * 16 + j;
#pragma unroll
            for (int n = 0; n < 2; n++) {
                int col = ccol + n * 16;
                float v = acc[m][n][j];
                if (mode == 0) {
                    if (add) v += add[(size_t)row * N + col];
                    ((float*)Cout)[(size_t)row * N + col] = v;
                } else if (mode == 1) {
                    ((f16*)Cout)[(size_t)row * N + col] = (f16)v;
                } else {
                    size_t o = (size_t)row * DMODEL;
                    if (col < DMODEL) ((f16*)Cout)[o + col] = (f16)v;
                    else if (col < 2 * DMODEL) p2[o + col - DMODEL] = (f16)v;
                    else p3[o + col - 2 * DMODEL] = (f16)v;
                }
            }
        }
}

// ---------------- MFMA scores ----------------
__global__ __launch_bounds__(256) void scoresm_k(const f16* __restrict__ qf,
                                                 const f16* __restrict__ kf,
                                                 f16* __restrict__ sc, int cb) {
    int h = blockIdx.z;
    int il0 = blockIdx.y * 64;
    int j0 = blockIdx.x * 64;
    __shared__ f16 Qf[64][72];
    __shared__ f16 Kf[64][72];
    int tid = threadIdx.x;
    {
        int r = tid >> 2, c0 = (tid & 3) * 16;
        const f16* p;
        p = qf + (size_t)(cb + il0 + r) * DMODEL + h * 64 + c0;
        *(uint4*)&Qf[r][c0] = *(const uint4*)p;
        *(uint4*)&Qf[r][c0 + 8] = *(const uint4*)(p + 8);
        p = kf + (size_t)(j0 + r) * DMODEL + h * 64 + c0;
        *(uint4*)&Kf[r][c0] = *(const uint4*)p;
        *(uint4*)&Kf[r][c0 + 8] = *(const uint4*)(p + 8);
    }
    __syncthreads();
    int lane = tid & 63, wave = tid >> 6;
    int wr = (wave >> 1) * 32, wc = (wave & 1) * 32;
    f32x4 acc[2][2];
#pragma unroll
    for (int m = 0; m < 2; m++)
#pragma unroll
        for (int n = 0; n < 2; n++) acc[m][n] = (f32x4){0.f, 0.f, 0.f, 0.f};
#pragma unroll
    for (int ks = 0; ks < 2; ks++) {
        int kof = ks * 32 + (lane >> 4) * 8;
        f16x8 aQ[2], bK[2];
#pragma unroll
        for (int m = 0; m < 2; m++)
            aQ[m] = *(const f16x8*)&Qf[wr + m * 16 + (lane & 15)][kof];
#pragma unroll
        for (int n = 0; n < 2; n++)
            bK[n] = *(const f16x8*)&Kf[wc + n * 16 + (lane & 15)][kof];
#pragma unroll
        for (int m = 0; m < 2; m++)
#pragma unroll
            for (int n = 0; n < 2; n++)
                acc[m][n] = __builtin_amdgcn_mfma_f32_16x16x32_f16(aQ[m], bK[n], acc[m][n], 0, 0, 0);
    }
#pragma unroll
    for (int m = 0; m < 2; m++)
#pragma unroll
        for (int j = 0; j < 4; j++) {
            int il = il0 + wr + m * 16 + (lane >> 4) * 4 + j;
#pragma unroll
            for (int n = 0; n < 2; n++) {
                int jj = j0 + wc + n * 16 + (lane & 15);
                sc[((size_t)h * CHUNK + il) * SEQ + jj] = (f16)(acc[m][n][j] * 0.125f);
            }
        }
}

// ---------------- logits_int -> f16 ----------------
__global__ __launch_bounds__(256) void copelogits_k(const f16* __restrict__ qf,
                                                    const float* __restrict__ pe,
                                                    f16* __restrict__ li) {
    int s1 = blockIdx.x;
    int tid = threadIdx.x;
    __shared__ float PE[DHEAD * NPOSE];
    __shared__ float QR[DMODEL];
    for (int i = tid; i < DHEAD * NPOSE; i += 256) PE[i] = pe[i];
    for (int i = tid; i < DMODEL; i += 256) QR[i] = (float)qf[(size_t)s1 * DMODEL + i];
    __syncthreads();
#pragma unroll
    for (int j = 0; j < 8; j++) {
        int o = j * 256 + tid;
        int h = o >> 7, n = o & 127;
        const float* qhp = &QR[h * DHEAD];
        float acc = 0.0f;
#pragma unroll 8
        for (int d = 0; d < DHEAD; d++) acc += qhp[d] * PE[d * NPOSE + n];
        li[(size_t)s1 * (NH * NPOSE) + o] = (f16)acc;
    }
}

// ---------------- fused CoPE: ILP scan + bias + f16 MFMA MLP + softmax -> P ----------------
#define CSTR 2052
__global__ __launch_bounds__(1024, 1) void cope_k(f16* __restrict__ sc,
                                                  const f16* __restrict__ li,
                                                  const float* __restrict__ w1,
                                                  const float* __restrict__ b1,
                                                  const float* __restrict__ w2,
                                                  const float* __restrict__ b2,
                                                  int cb) {
    __shared__ f16 C[32 * CSTR];
    __shared__ uint_t Lif2[NH * 130];
    __shared__ f16 HMB[16][16 * 36];
    int r = blockIdx.x;
    int tid = threadIdx.x;
    int lane = tid & 63, wv = tid >> 6;

    // prefetch own head's score row into registers (4 x uint4 = 32 f16)
    const f16* srow = sc + ((size_t)wv * CHUNK + r) * SEQ;
    HF8 rv[4];
#pragma unroll
    for (int c = 0; c < 4; c++) rv[c].u4 = *(const uint4*)&srow[c * 512 + lane * 8];

    // per-wave Lif2 staging (own head only -> no cross-wave barrier needed)
    {
        const f16* lh = li + (size_t)(cb + r) * (NH * NPOSE) + wv * NPOSE;
#pragma unroll
        for (int e = 0; e < 2; e++) {
            int n = lane + e * 64;
            U1H2 pk;
            pk.h[0] = lh[n];
            pk.h[1] = lh[(n < NPOSE - 1) ? n + 1 : NPOSE - 1];
            Lif2[wv * 130 + n] = pk.u;
        }
    }

    // suffix scan with 4 INDEPENDENT interleaved chains + carry resolution,
    // then bias interp; writes score row + bias row into LDS.
    {
        f16* crow = &C[wv * CSTR];
        f16* brow = &C[(16 + wv) * CSTR];
        const uint_t* lrow = &Lif2[wv * 130];
        float g[4][8];
        float S[4];
#pragma unroll
        for (int c = 0; c < 4; c++) {
            HF8 sv = rv[c];
            float s = 0.0f;
#pragma unroll
            for (int e = 0; e < 8; e++) {
                g[c][e] = sigm((float)sv.h[e]);
                s += g[c][e];
            }
            S[c] = s;
        }
        // 4 independent suffix-scan chains, interleaved for ILP
#pragma unroll
        for (int dd = 1; dd < 64; dd <<= 1) {
#pragma unroll
            for (int c = 0; c < 4; c++) {
                float o = __shfl_down(S[c], dd, 64);
                S[c] = (lane + dd < 64) ? S[c] + o : S[c];
            }
        }
        float tot[4];
#pragma unroll
        for (int c = 0; c < 4; c++) tot[c] = __shfl(S[c], 0, 64);
        // same accumulation order as the original right-to-left loop:
        float carry[4];
        carry[3] = 0.0f;
        carry[2] = tot[3];
        carry[1] = tot[3] + tot[2];
        carry[0] = carry[1] + tot[1];
#pragma unroll
        for (int c = 0; c < 4; c++) {
            float p = S[c] + carry[c];
            HF8 bo;
#pragma unroll
            for (int e = 0; e < 8; e++) {
                float pos = fminf(p, 127.0f);
                int fl = (int)pos;
                float fr = pos - (float)fl;
                U1H2 lv;
                lv.u = lrow[fl];
                float lf = (float)lv.h[0];
                bo.h[e] = (f16)(lf + ((float)lv.h[1] - lf) * fr);
                p -= g[c][e];
            }
            int t = c * 512 + lane * 8;
            *(uint4*)&crow[t] = rv[c].u4;
            *(uint4*)&brow[t] = bo.u4;
        }
    }
    __syncthreads();

    // MLP weight fragments (f16)
    int fkg = lane >> 4;
    int fc = lane & 15;
    HF8 w1f[2], w2f;
    float b1v[2], b2v;
#pragma unroll
    for (int half = 0; half < 2; half++) {
#pragma unroll
        for (int j = 0; j < 8; j++)
            w1f[half].h[j] = (f16)w1[(fkg * 8 + j) * MLPWID + half * 16 + fc];
        b1v[half] = b1[half * 16 + fc];
    }
#pragma unroll
    for (int j = 0; j < 8; j++) w2f.h[j] = (f16)w2[(fkg * 8 + j) * NH + fc];
    b2v = b2[fc];

    // f16 MFMA MLP over t-tiles of 16; wave wv does tiles wv, wv+16, ... (8 tiles)
    f16* hmb = HMB[wv];
#pragma unroll 2
    for (int tt = wv; tt < SEQ / 16; tt += 16) {
        int t0 = tt * 16;
        HF8 af;
#pragma unroll
        for (int j = 0; j < 8; j++) af.h[j] = C[(fkg * 8 + j) * CSTR + t0 + fc];
        f32x4 acc0 = (f32x4){b1v[0], b1v[0], b1v[0], b1v[0]};
        f32x4 acc1 = (f32x4){b1v[1], b1v[1], b1v[1], b1v[1]};
        acc0 = __builtin_amdgcn_mfma_f32_16x16x32_f16(af.v, w1f[0].v, acc0, 0, 0, 0);
        acc1 = __builtin_amdgcn_mfma_f32_16x16x32_f16(af.v, w1f[1].v, acc1, 0, 0, 0);
#pragma unroll
        for (int j2 = 0; j2 < 4; j2++) {
            int p = fkg * 4 + j2;
            float h0 = acc0[j2]; h0 = h0 * sigm(h0);
            float h1 = acc1[j2]; h1 = h1 * sigm(h1);
            hmb[p * 36 + fc] = (f16)h0;
            hmb[p * 36 + 16 + fc] = (f16)h1;
        }
        HF8 hf;
        hf.u2[0] = *(const uint2*)&hmb[fc * 36 + fkg * 8];
        hf.u2[1] = *(const uint2*)&hmb[fc * 36 + fkg * 8 + 4];
        f32x4 acc2 = (f32x4){b2v, b2v, b2v, b2v};
        acc2 = __builtin_amdgcn_mfma_f32_16x16x32_f16(hf.v, w2f.v, acc2, 0, 0, 0);
#pragma unroll
        for (int j2 = 0; j2 < 4; j2 += 2) {
            uint_t* pp = (uint_t*)&C[fc * CSTR + t0 + fkg * 4 + j2];
            U1H2 old, neu;
            old.u = *pp;
            neu.h[0] = (f16)((float)old.h[0] + acc2[j2]);
            neu.h[1] = (f16)((float)old.h[1] + acc2[j2 + 1]);
            *pp = neu.u;
        }
    }
    __syncthreads();

    // fused softmax: wave wv -> head wv; write normalized P (f16, uint4) to global
    {
        const f16* row = &C[wv * CSTR];
        float vals[32];
        float m = -1e30f;
#pragma unroll
        for (int c = 0; c < 4; c++) {
            HF8 sv;
            sv.u4 = *(const uint4*)&row[c * 512 + lane * 8];
#pragma unroll
            for (int e = 0; e < 8; e++) {
                vals[c * 8 + e] = (float)sv.h[e];
                m = fmaxf(m, vals[c * 8 + e]);
            }
        }
#pragma unroll
        for (int d = 1; d < 64; d <<= 1) m = fmaxf(m, __shfl_xor(m, d, 64));
        float s = 0.0f;
#pragma unroll
        for (int c = 0; c < 32; c++) {
            vals[c] = __expf(vals[c] - m);
            s += vals[c];
        }
#pragma unroll
        for (int d = 1; d < 64; d <<= 1) s += __shfl_xor(s, d, 64);
        float ri = __builtin_amdgcn_rcpf(s);
        f16* dst = sc + ((size_t)wv * CHUNK + r) * SEQ;
#pragma unroll
        for (int c = 0; c < 4; c++) {
            HF8 po;
#pragma unroll
            for (int e = 0; e < 8; e++) po.h[e] = (f16)(vals[c * 8 + e] * ri);
            *(uint4*)&dst[c * 512 + lane * 8] = po.u4;
        }
    }
}

// ---------------- f16 MFMA PV ----------------
__global__ __launch_bounds__(256) void pvm_k(const f16* __restrict__ scP,
                                             const ushort_t* __restrict__ vt,
                                             f16* __restrict__ aob, int cb) {
    int h = blockIdx.y;
    int s0 = blockIdx.x * 32;
    __shared__ f16 P[32][72];
    __shared__ f16 Vt[64][72];
    int tid = threadIdx.x;
    int lane = tid & 63, wave = tid >> 6;
    int wr = (wave >> 1) * 16, wc = (wave & 1) * 32;
    f32x4 acc[2];
    acc[0] = (f32x4){0.f, 0.f, 0.f, 0.f};
    acc[1] = (f32x4){0.f, 0.f, 0.f, 0.f};
    int pr = tid >> 3, pc = (tid & 7) * 8;
    int vr = tid >> 2, vc = (tid & 3) * 16;
    for (int t0 = 0; t0 < SEQ; t0 += 64) {
        {
            *(uint4*)&P[pr][pc] =
                *(const uint4*)(scP + ((size_t)h * CHUNK + s0 + pr) * SEQ + t0 + pc);
            const ushort_t* vp = vt + ((size_t)h * 64 + vr) * SEQ + t0 + vc;
            *(uint4*)&Vt[vr][vc] = *(const uint4*)vp;
            *(uint4*)&Vt[vr][vc + 8] = *(const uint4*)(vp + 8);
        }
        __syncthreads();
#pragma unroll
        for (int ks = 0; ks < 2; ks++) {
            int kof = ks * 32 + (lane >> 4) * 8;
            f16x8 pa = *(const f16x8*)&P[wr + (lane & 15)][kof];
#pragma unroll
            for (int n = 0; n < 2; n++) {
                f16x8 vb = *(const f16x8*)&Vt[wc + n * 16 + (lane & 15)][kof];
                acc[n] = __builtin_amdgcn_mfma_f32_16x16x32_f16(pa, vb, acc[n], 0, 0, 0);
            }
        }
        __syncthreads();
    }
#pragma unroll
    for (int j = 0; j < 4; j++) {
        int s = cb + s0 + wr + (lane >> 4) * 4 + j;
#pragma unroll
        for (int n = 0; n < 2; n++) {
            int d = h * 64 + wc + n * 16 + (lane & 15);
            aob[(size_t)s * DMODEL + d] = (f16)acc[n][j];
        }
    }
}

extern "C" void kernel_launch(void* const* d_in, const int* in_sizes, int n_in,
                              void* d_out, int out_size, void* d_ws, size_t ws_size,
                              hipStream_t stream) {
    const float* x = (const float*)d_in[0];
    const float* wq = (const float*)d_in[1];
    const float* wk = (const float*)d_in[2];
    const float* wv = (const float*)d_in[3];
    const float* wo = (const float*)d_in[4];
    const float* pos_emb = (const float*)d_in[5];
    const float* mlp_w1 = (const float*)d_in[6];
    const float* mlp_b1 = (const float*)d_in[7];
    const float* mlp_w2 = (const float*)d_in[8];
    const float* mlp_b2 = (const float*)d_in[9];
    const float* ffn_w1 = (const float*)d_in[10];
    const float* ffn_w2 = (const float*)d_in[11];
    const float* ffn_w3 = (const float*)d_in[12];
    const float* attn_norm_w = (const float*)d_in[13];
    const float* ffn_norm_w = (const float*)d_in[14];
    float* out = (float*)d_out;

    char* ws = (char*)d_ws;
    const size_t MB = 1024 * 1024;
    f16* nxb = (f16*)(ws + 0);               // 0-4
    f16* qf = (f16*)(ws + 4 * MB);           // 4-8   (phase C: nxb2)
    f16* kf = (f16*)(ws + 8 * MB);           // 8-12  (phase C: g1b 8-24)
    f16* vb = (f16*)(ws + 12 * MB);          // 12-16
    f16* vt = (f16*)(ws + 16 * MB);          // 16-20
    f16* li = (f16*)(ws + 20 * MB);          // 20-28
    f16* aob = (f16*)(ws + 28 * MB);         // 28-32
    float* x1 = (float*)(ws + 32 * MB);      // 32-40
    f16* wqkvt = (f16*)(ws + 40 * MB);       // 40-46 (phase 1)
    f16* sc = (f16*)(ws + 40 * MB);          // 40-104 (phase 2, CHUNK=1024)
    f16* wot = (f16*)(ws + 40 * MB);         // 40-42 (phase B)
    f16* w13t = (f16*)(ws + 40 * MB);        // 40-56 (phase C, interleaved)
    f16* w2t = (f16*)(ws + 56 * MB);         // 56-64
    f16* nxb2 = (f16*)(ws + 4 * MB);
    f16* g1b = (f16*)(ws + 8 * MB);          // 8-24

    // ---- phase 1: norm + fused QKV (64-tile, 1536 blocks) ----
    transconv3_k<<<dim3(DMODEL / 64, DMODEL / 64, 3), 256, 0, stream>>>(wq, wk, wv, wqkvt);
    rmsnormf_k<<<SEQ, 256, 0, stream>>>(x, attn_norm_w, nxb);
    gemm64_k<<<dim3(3 * DMODEL / 64, SEQ / 64), 256, 0, stream>>>(
        nxb, wqkvt, nullptr, qf, SEQ, 3 * DMODEL, DMODEL, 2, kf, vb);
    copelogits_k<<<SEQ, 256, 0, stream>>>(qf, pos_emb, li);
    tv_k<<<dim3(SEQ / 64, NH), 256, 0, stream>>>((const ushort_t*)vb, (ushort_t*)vt);

    // ---- phase 2: attention chunks ----
    for (int ch = 0; ch < NCH; ch++) {
        int cb = ch * CHUNK;
        scoresm_k<<<dim3(SEQ / 64, CHUNK / 64, NH), 256, 0, stream>>>(qf, kf, sc, cb);
        cope_k<<<CHUNK, 1024, 0, stream>>>(sc, li, mlp_w1, mlp_b1, mlp_w2, mlp_b2, cb);
        pvm_k<<<dim3(CHUNK / 32, NH), 256, 0, stream>>>(sc, (const ushort_t*)vt, aob, cb);
    }

    // ---- phase B: out @ wo + x (64-tile, 512 blocks) ----
    transconv_k<<<dim3(DMODEL / 64, DMODEL / 64), 256, 0, stream>>>(wo, wot, DMODEL, DMODEL);
    gemm64_k<<<dim3(DMODEL / 64, SEQ / 64), 256, 0, stream>>>(
        aob, wot, x, x1, SEQ, DMODEL, DMODEL, 0, nullptr, nullptr);

    // ---- phase C: FFN ----
    rmsnormf_k<<<SEQ, 256, 0, stream>>>(x1, ffn_norm_w, nxb2);
    transconv2_k<<<dim3(FFDIM / 64, DMODEL / 64), 256, 0, stream>>>(ffn_w1, ffn_w3, w13t, DMODEL, FFDIM);
    transconv_k<<<dim3(DMODEL / 64, FFDIM / 64), 256, 0, stream>>>(ffn_w2, w2t, FFDIM, DMODEL);
    gemm128_k<<<dim3(2 * FFDIM / 128, SEQ / 128), 256, 0, stream>>>(
        nxb2, w13t, nullptr, g1b, SEQ, 2 * FFDIM, DMODEL, 4);
    gemm64_k<<<dim3(DMODEL / 64, SEQ / 64), 256, 0, stream>>>(
        g1b, w2t, x1, out, SEQ, DMODEL, FFDIM, 0, nullptr, nullptr);
}

// Round 18
// 438.093 us; speedup vs baseline: 1.0073x; 1.0073x over previous
//
#include <hip/hip_runtime.h>
#include <hip/hip_bf16.h>
#include <hip/hip_fp16.h>
#include <math.h>

#define SEQ 2048
#define DMODEL 1024
#define NH 16
#define DHEAD 64
#define FFDIM 4096
#define NPOSE 128
#define MLPWID 32
#define EPSV 1e-5f
#define CHUNK 1024
#define NCH (SEQ / CHUNK)

typedef unsigned short ushort_t;
typedef unsigned int uint_t;
typedef _Float16 f16;
typedef __attribute__((ext_vector_type(8))) _Float16 f16x8;
typedef __attribute__((ext_vector_type(4))) float f32x4;

union HF8 { f16x8 v; f16 h[8]; ushort_t s[8]; uint2 u2[2]; uint4 u4; };
union U1H2 { uint_t u; f16 h[2]; };
union U2H4 { uint2 u; f16 h[4]; };

__device__ __forceinline__ float sigm(float x) {
    return __builtin_amdgcn_rcpf(1.0f + __expf(-x));
}
__device__ __forceinline__ void gl_lds16(const void* g, void* l) {
    __builtin_amdgcn_global_load_lds((const __attribute__((address_space(1))) uint_t*)g,
                                     (__attribute__((address_space(3))) uint_t*)l, 16, 0, 0);
}

// ---------------- RMSNorm, f16 out ----------------
__global__ __launch_bounds__(256) void rmsnormf_k(const float* __restrict__ x,
                                                  const float* __restrict__ w,
                                                  f16* __restrict__ o) {
    int row = blockIdx.x;
    int tid = threadIdx.x;
    const float4* xr = (const float4*)(x + (size_t)row * DMODEL);
    float4 v = xr[tid];
    float ss = v.x * v.x + v.y * v.y + v.z * v.z + v.w * v.w;
#pragma unroll
    for (int d = 1; d < 64; d <<= 1) ss += __shfl_xor(ss, d, 64);
    __shared__ float red[4];
    int lane = tid & 63, wv = tid >> 6;
    if (lane == 0) red[wv] = ss;
    __syncthreads();
    float tot = red[0] + red[1] + red[2] + red[3];
    float r = rsqrtf(tot / (float)DMODEL + EPSV);
    const float4* wr = (const float4*)w;
    float4 wv4 = wr[tid];
    U2H4 ob;
    ob.h[0] = (f16)(v.x * r * wv4.x);
    ob.h[1] = (f16)(v.y * r * wv4.y);
    ob.h[2] = (f16)(v.z * r * wv4.z);
    ob.h[3] = (f16)(v.w * r * wv4.w);
    ((uint2*)(o + (size_t)row * DMODEL))[tid] = ob.u;
}

// ---------------- V transpose ----------------
__global__ __launch_bounds__(256) void tv_k(const ushort_t* __restrict__ vb,
                                            ushort_t* __restrict__ vt) {
    int h = blockIdx.y, t0 = blockIdx.x * 64;
    __shared__ ushort_t T[64][76];
    int tid = threadIdx.x;
#pragma unroll
    for (int it = 0; it < 2; it++) {
        int a = tid + it * 256;
        int t = a >> 3, c8 = (a & 7) * 8;
        HF8 v;
        v.u4 = *(const uint4*)(vb + (size_t)(t0 + t) * DMODEL + h * 64 + c8);
#pragma unroll
        for (int j = 0; j < 8; j++) T[c8 + j][t] = v.s[j];
    }
    __syncthreads();
#pragma unroll
    for (int it = 0; it < 2; it++) {
        int a = tid + it * 256;
        int d = a >> 3, c8 = (a & 7) * 8;
        HF8 o;
#pragma unroll
        for (int j = 0; j < 8; j++) o.s[j] = T[d][c8 + j];
        *(uint4*)(vt + ((size_t)h * 64 + d) * SEQ + t0 + c8) = o.u4;
    }
}

// ---------------- weight transpose+convert: f32[K][N] -> f16[N][K] ----------------
__global__ __launch_bounds__(256) void transconv_k(const float* __restrict__ in,
                                                   f16* __restrict__ out,
                                                   int K, int N) {
    __shared__ f16 T[64][72];
    int k0 = blockIdx.y * 64, n0 = blockIdx.x * 64;
    int tid = threadIdx.x;
    int r = tid >> 4, c4 = (tid & 15) * 4;
#pragma unroll
    for (int i = 0; i < 4; i++) {
        float4 v = *(const float4*)(in + (size_t)(k0 + r + i * 16) * N + n0 + c4);
        T[c4 + 0][r + i * 16] = (f16)v.x;
        T[c4 + 1][r + i * 16] = (f16)v.y;
        T[c4 + 2][r + i * 16] = (f16)v.z;
        T[c4 + 3][r + i * 16] = (f16)v.w;
    }
    __syncthreads();
    int n = tid >> 2, kk = (tid & 3) * 16;
    uint4* dst = (uint4*)(out + (size_t)(n0 + n) * K + k0 + kk);
    dst[0] = *(const uint4*)&T[n][kk];
    dst[1] = *(const uint4*)&T[n][kk + 8];
}

// ---------------- 3-way weight transpose (QKV) via blockIdx.z ----------------
__global__ __launch_bounds__(256) void transconv3_k(const float* __restrict__ w0,
                                                    const float* __restrict__ w1p,
                                                    const float* __restrict__ w2p,
                                                    f16* __restrict__ out) {
    const int K = DMODEL, N = DMODEL;
    const float* in = (blockIdx.z == 0) ? w0 : (blockIdx.z == 1) ? w1p : w2p;
    f16* o = out + (size_t)blockIdx.z * DMODEL * DMODEL;
    __shared__ f16 T[64][72];
    int k0 = blockIdx.y * 64, n0 = blockIdx.x * 64;
    int tid = threadIdx.x;
    int r = tid >> 4, c4 = (tid & 15) * 4;
#pragma unroll
    for (int i = 0; i < 4; i++) {
        float4 v = *(const float4*)(in + (size_t)(k0 + r + i * 16) * N + n0 + c4);
        T[c4 + 0][r + i * 16] = (f16)v.x;
        T[c4 + 1][r + i * 16] = (f16)v.y;
        T[c4 + 2][r + i * 16] = (f16)v.z;
        T[c4 + 3][r + i * 16] = (f16)v.w;
    }
    __syncthreads();
    int n = tid >> 2, kk = (tid & 3) * 16;
    uint4* dst = (uint4*)(o + (size_t)(n0 + n) * K + k0 + kk);
    dst[0] = *(const uint4*)&T[n][kk];
    dst[1] = *(const uint4*)&T[n][kk + 8];
}

// ---------------- w1/w3 transpose+convert, row-interleaved ----------------
__global__ __launch_bounds__(256) void transconv2_k(const float* __restrict__ w1,
                                                    const float* __restrict__ w3,
                                                    f16* __restrict__ out,
                                                    int K, int N) {
    __shared__ f16 T[64][72];
    int k0 = blockIdx.y * 64, n0 = blockIdx.x * 64;
    int tid = threadIdx.x;
    int r = tid >> 4, c4 = (tid & 15) * 4;
    int n = tid >> 2, kk = (tid & 3) * 16;
#pragma unroll
    for (int half = 0; half < 2; half++) {
        const float* in = half ? w3 : w1;
#pragma unroll
        for (int i = 0; i < 4; i++) {
            float4 v = *(const float4*)(in + (size_t)(k0 + r + i * 16) * N + n0 + c4);
            T[c4 + 0][r + i * 16] = (f16)v.x;
            T[c4 + 1][r + i * 16] = (f16)v.y;
            T[c4 + 2][r + i * 16] = (f16)v.z;
            T[c4 + 3][r + i * 16] = (f16)v.w;
        }
        __syncthreads();
        int gc = n0 + n;
        int rp = (gc >> 4) * 32 + (gc & 15) + half * 16;
        uint4* dst = (uint4*)(out + (size_t)rp * K + k0 + kk);
        dst[0] = *(const uint4*)&T[n][kk];
        dst[1] = *(const uint4*)&T[n][kk + 8];
        __syncthreads();
    }
}

// ---------------- f16 MFMA GEMM 128x128 (TN), XCD-swizzled ----------------
// mode 0: f32 out (+add). mode 1: f16 out. mode 4: w1w3-interleaved silu-mul.
__global__ __launch_bounds__(256) void gemm128_k(const f16* __restrict__ A,
                                                 const f16* __restrict__ Bt,
                                                 const float* __restrict__ add,
                                                 void* __restrict__ Cout,
                                                 int M, int N, int K, int mode) {
    __shared__ f16 Al[128 * 32];
    __shared__ f16 Bl[128 * 32];
    int tid = threadIdx.x;
    int lane = tid & 63, wave = tid >> 6;
    int gx = gridDim.x, gy = gridDim.y;
    int nwg = gx * gy;
    int bx = blockIdx.x, by = blockIdx.y;
    if ((nwg & 7) == 0) {
        int flat = by * gx + bx;
        int cpx = nwg >> 3;
        int l = (flat & 7) * cpx + (flat >> 3);
        bx = l / gy;
        by = l % gy;
    }
    int brow = by * 128, bcol = bx * 128;
    int wr = (wave >> 1) * 64, wc = (wave & 1) * 64;
    f32x4 acc[4][4];
#pragma unroll
    for (int m = 0; m < 4; m++)
#pragma unroll
        for (int n = 0; n < 4; n++) acc[m][n] = (f32x4){0.f, 0.f, 0.f, 0.f};

    const f16* Ag = A + (size_t)(brow + (tid >> 2)) * K + (tid & 3) * 8;
    const f16* Bg = Bt + (size_t)(bcol + (tid >> 2)) * K + (tid & 3) * 8;
    f16* Ald = &Al[wave * 512];
    f16* Bld = &Bl[wave * 512];
    size_t rstep = (size_t)64 * K;

    for (int k0 = 0; k0 < K; k0 += 32) {
        gl_lds16(Ag + k0, Ald);
        gl_lds16(Ag + k0 + rstep, Ald + 2048);
        gl_lds16(Bg + k0, Bld);
        gl_lds16(Bg + k0 + rstep, Bld + 2048);
        __syncthreads();
        f16x8 af[4], bfr[4];
        int arow = wr + (lane & 15);
        int brw = wc + (lane & 15);
        int kof = (lane >> 4) * 8;
#pragma unroll
        for (int m = 0; m < 4; m++) af[m] = *(const f16x8*)&Al[(arow + m * 16) * 32 + kof];
#pragma unroll
        for (int n = 0; n < 4; n++) bfr[n] = *(const f16x8*)&Bl[(brw + n * 16) * 32 + kof];
#pragma unroll
        for (int m = 0; m < 4; m++)
#pragma unroll
            for (int n = 0; n < 4; n++)
                acc[m][n] = __builtin_amdgcn_mfma_f32_16x16x32_f16(af[m], bfr[n], acc[m][n], 0, 0, 0);
        __syncthreads();
    }
    int crow0 = brow + wr + (lane >> 4) * 4;
    int ccol = bcol + wc + (lane & 15);
#pragma unroll
    for (int m = 0; m < 4; m++)
#pragma unroll
        for (int j = 0; j < 4; j++) {
            int row = crow0 + m * 16 + j;
            if (mode == 4) {
#pragma unroll
                for (int n = 0; n < 4; n += 2) {
                    int c = ccol + n * 16;
                    int colOut = (c >> 5) * 16 + (c & 15);
                    float v1 = acc[m][n][j];
                    float v3 = acc[m][n + 1][j];
                    ((f16*)Cout)[(size_t)row * (N / 2) + colOut] =
                        (f16)(v1 * sigm(v1) * v3);
                }
            } else {
#pragma unroll
                for (int n = 0; n < 4; n++) {
                    int col = ccol + n * 16;
                    float v = acc[m][n][j];
                    if (mode == 0) {
                        if (add) v += add[(size_t)row * N + col];
                        ((float*)Cout)[(size_t)row * N + col] = v;
                    } else {
                        ((f16*)Cout)[(size_t)row * N + col] = (f16)v;
                    }
                }
            }
        }
}

// ---------------- f16 MFMA GEMM 64x64 (TN), XCD-swizzled ----------------
// mode 0: f32 out (+add). mode 1: f16. mode 2: qkv split (Cout=q, p2=k, p3=v).
__global__ __launch_bounds__(256) void gemm64_k(const f16* __restrict__ A,
                                                const f16* __restrict__ Bt,
                                                const float* __restrict__ add,
                                                void* __restrict__ Cout,
                                                int M, int N, int K, int mode,
                                                f16* __restrict__ p2,
                                                f16* __restrict__ p3) {
    __shared__ f16 Al[64 * 32];
    __shared__ f16 Bl[64 * 32];
    int tid = threadIdx.x;
    int lane = tid & 63, wave = tid >> 6;
    int gx = gridDim.x, gy = gridDim.y;
    int nwg = gx * gy;
    int bx = blockIdx.x, by = blockIdx.y;
    if ((nwg & 7) == 0) {
        int flat = by * gx + bx;
        int cpx = nwg >> 3;
        int l = (flat & 7) * cpx + (flat >> 3);
        bx = l / gy;
        by = l % gy;
    }
    int brow = by * 64, bcol = bx * 64;
    int wr = (wave >> 1) * 32, wc = (wave & 1) * 32;
    f32x4 acc[2][2];
#pragma unroll
    for (int m = 0; m < 2; m++)
#pragma unroll
        for (int n = 0; n < 2; n++) acc[m][n] = (f32x4){0.f, 0.f, 0.f, 0.f};

    const f16* Ag = A + (size_t)(brow + (tid >> 2)) * K + (tid & 3) * 8;
    const f16* Bg = Bt + (size_t)(bcol + (tid >> 2)) * K + (tid & 3) * 8;
    f16* Ald = &Al[wave * 512];
    f16* Bld = &Bl[wave * 512];

    for (int k0 = 0; k0 < K; k0 += 32) {
        gl_lds16(Ag + k0, Ald);
        gl_lds16(Bg + k0, Bld);
        __syncthreads();
        f16x8 af[2], bfr[2];
        int kof = (lane >> 4) * 8;
#pragma unroll
        for (int m = 0; m < 2; m++)
            af[m] = *(const f16x8*)&Al[(wr + m * 16 + (lane & 15)) * 32 + kof];
#pragma unroll
        for (int n = 0; n < 2; n++)
            bfr[n] = *(const f16x8*)&Bl[(wc + n * 16 + (lane & 15)) * 32 + kof];
#pragma unroll
        for (int m = 0; m < 2; m++)
#pragma unroll
            for (int n = 0; n < 2; n++)
                acc[m][n] = __builtin_amdgcn_mfma_f32_16x16x32_f16(af[m], bfr[n], acc[m][n], 0, 0, 0);
        __syncthreads();
    }
    int crow0 = brow + wr + (lane >> 4) * 4;
    int ccol = bcol + wc + (lane & 15);
#pragma unroll
    for (int m = 0; m < 2; m++)
#pragma unroll
        for (int j = 0; j < 4; j++) {
            int row = crow0 + m * 16 + j;
#pragma unroll
            for (int n = 0; n < 2; n++) {
                int col = ccol + n * 16;
                float v = acc[m][n][j];
                if (mode == 0) {
                    if (add) v += add[(size_t)row * N + col];
                    ((float*)Cout)[(size_t)row * N + col] = v;
                } else if (mode == 1) {
                    ((f16*)Cout)[(size_t)row * N + col] = (f16)v;
                } else {
                    size_t o = (size_t)row * DMODEL;
                    if (col < DMODEL) ((f16*)Cout)[o + col] = (f16)v;
                    else if (col < 2 * DMODEL) p2[o + col - DMODEL] = (f16)v;
                    else p3[o + col - 2 * DMODEL] = (f16)v;
                }
            }
        }
}

// ---------------- MFMA scores, 128x128 tile: sc[h][il][j] = qf_i . kf_j / 8 ----------------
__global__ __launch_bounds__(256) void scoresm_k(const f16* __restrict__ qf,
                                                 const f16* __restrict__ kf,
                                                 f16* __restrict__ sc, int cb) {
    int h = blockIdx.z;
    int il0 = blockIdx.y * 128;
    int j0 = blockIdx.x * 128;
    __shared__ f16 Qf[128][72];
    __shared__ f16 Kf[128][72];
    int tid = threadIdx.x;
#pragma unroll
    for (int i = 0; i < 4; i++) {
        int row = i * 32 + (tid >> 3);
        int c8 = (tid & 7) * 8;
        *(uint4*)&Qf[row][c8] =
            *(const uint4*)(qf + (size_t)(cb + il0 + row) * DMODEL + h * 64 + c8);
        *(uint4*)&Kf[row][c8] =
            *(const uint4*)(kf + (size_t)(j0 + row) * DMODEL + h * 64 + c8);
    }
    __syncthreads();
    int lane = tid & 63, wave = tid >> 6;
    int wr = (wave >> 1) * 64, wc = (wave & 1) * 64;
    f32x4 acc[4][4];
#pragma unroll
    for (int m = 0; m < 4; m++)
#pragma unroll
        for (int n = 0; n < 4; n++) acc[m][n] = (f32x4){0.f, 0.f, 0.f, 0.f};
#pragma unroll
    for (int ks = 0; ks < 2; ks++) {
        int kof = ks * 32 + (lane >> 4) * 8;
        f16x8 aQ[4], bK[4];
#pragma unroll
        for (int m = 0; m < 4; m++)
            aQ[m] = *(const f16x8*)&Qf[wr + m * 16 + (lane & 15)][kof];
#pragma unroll
        for (int n = 0; n < 4; n++)
            bK[n] = *(const f16x8*)&Kf[wc + n * 16 + (lane & 15)][kof];
#pragma unroll
        for (int m = 0; m < 4; m++)
#pragma unroll
            for (int n = 0; n < 4; n++)
                acc[m][n] = __builtin_amdgcn_mfma_f32_16x16x32_f16(aQ[m], bK[n], acc[m][n], 0, 0, 0);
    }
#pragma unroll
    for (int m = 0; m < 4; m++)
#pragma unroll
        for (int j = 0; j < 4; j++) {
            int il = il0 + wr + m * 16 + (lane >> 4) * 4 + j;
#pragma unroll
            for (int n = 0; n < 4; n++) {
                int jj = j0 + wc + n * 16 + (lane & 15);
                sc[((size_t)h * CHUNK + il) * SEQ + jj] = (f16)(acc[m][n][j] * 0.125f);
            }
        }
}

// ---------------- logits_int -> f16 ----------------
__global__ __launch_bounds__(256) void copelogits_k(const f16* __restrict__ qf,
                                                    const float* __restrict__ pe,
                                                    f16* __restrict__ li) {
    int s1 = blockIdx.x;
    int tid = threadIdx.x;
    __shared__ float PE[DHEAD * NPOSE];
    __shared__ float QR[DMODEL];
    for (int i = tid; i < DHEAD * NPOSE; i += 256) PE[i] = pe[i];
    for (int i = tid; i < DMODEL; i += 256) QR[i] = (float)qf[(size_t)s1 * DMODEL + i];
    __syncthreads();
#pragma unroll
    for (int j = 0; j < 8; j++) {
        int o = j * 256 + tid;
        int h = o >> 7, n = o & 127;
        const float* qhp = &QR[h * DHEAD];
        float acc = 0.0f;
#pragma unroll 8
        for (int d = 0; d < DHEAD; d++) acc += qhp[d] * PE[d * NPOSE + n];
        li[(size_t)s1 * (NH * NPOSE) + o] = (f16)acc;
    }
}

// ---------------- fused CoPE: ILP scan + bias + f16 MFMA MLP + softmax -> P ----------------
#define CSTR 2052
__global__ __launch_bounds__(1024, 1) void cope_k(f16* __restrict__ sc,
                                                  const f16* __restrict__ li,
                                                  const float* __restrict__ w1,
                                                  const float* __restrict__ b1,
                                                  const float* __restrict__ w2,
                                                  const float* __restrict__ b2,
                                                  int cb) {
    __shared__ f16 C[32 * CSTR];
    __shared__ uint_t Lif2[NH * 130];
    __shared__ f16 HMB[16][16 * 36];
    int r = blockIdx.x;
    int tid = threadIdx.x;
    int lane = tid & 63, wv = tid >> 6;

    const f16* srow = sc + ((size_t)wv * CHUNK + r) * SEQ;
    HF8 rv[4];
#pragma unroll
    for (int c = 0; c < 4; c++) rv[c].u4 = *(const uint4*)&srow[c * 512 + lane * 8];

    {
        const f16* lh = li + (size_t)(cb + r) * (NH * NPOSE) + wv * NPOSE;
#pragma unroll
        for (int e = 0; e < 2; e++) {
            int n = lane + e * 64;
            U1H2 pk;
            pk.h[0] = lh[n];
            pk.h[1] = lh[(n < NPOSE - 1) ? n + 1 : NPOSE - 1];
            Lif2[wv * 130 + n] = pk.u;
        }
    }

    {
        f16* crow = &C[wv * CSTR];
        f16* brow = &C[(16 + wv) * CSTR];
        const uint_t* lrow = &Lif2[wv * 130];
        float g[4][8];
        float S[4];
#pragma unroll
        for (int c = 0; c < 4; c++) {
            HF8 sv = rv[c];
            float s = 0.0f;
#pragma unroll
            for (int e = 0; e < 8; e++) {
                g[c][e] = sigm((float)sv.h[e]);
                s += g[c][e];
            }
            S[c] = s;
        }
#pragma unroll
        for (int dd = 1; dd < 64; dd <<= 1) {
#pragma unroll
            for (int c = 0; c < 4; c++) {
                float o = __shfl_down(S[c], dd, 64);
                S[c] = (lane + dd < 64) ? S[c] + o : S[c];
            }
        }
        float tot[4];
#pragma unroll
        for (int c = 0; c < 4; c++) tot[c] = __shfl(S[c], 0, 64);
        float carry[4];
        carry[3] = 0.0f;
        carry[2] = tot[3];
        carry[1] = tot[3] + tot[2];
        carry[0] = carry[1] + tot[1];
#pragma unroll
        for (int c = 0; c < 4; c++) {
            float p = S[c] + carry[c];
            HF8 bo;
#pragma unroll
            for (int e = 0; e < 8; e++) {
                float pos = fminf(p, 127.0f);
                int fl = (int)pos;
                float fr = pos - (float)fl;
                U1H2 lv;
                lv.u = lrow[fl];
                float lf = (float)lv.h[0];
                bo.h[e] = (f16)(lf + ((float)lv.h[1] - lf) * fr);
                p -= g[c][e];
            }
            int t = c * 512 + lane * 8;
            *(uint4*)&crow[t] = rv[c].u4;
            *(uint4*)&brow[t] = bo.u4;
        }
    }
    __syncthreads();

    int fkg = lane >> 4;
    int fc = lane & 15;
    HF8 w1f[2], w2f;
    float b1v[2], b2v;
#pragma unroll
    for (int half = 0; half < 2; half++) {
#pragma unroll
        for (int j = 0; j < 8; j++)
            w1f[half].h[j] = (f16)w1[(fkg * 8 + j) * MLPWID + half * 16 + fc];
        b1v[half] = b1[half * 16 + fc];
    }
#pragma unroll
    for (int j = 0; j < 8; j++) w2f.h[j] = (f16)w2[(fkg * 8 + j) * NH + fc];
    b2v = b2[fc];

    f16* hmb = HMB[wv];
#pragma unroll 2
    for (int tt = wv; tt < SEQ / 16; tt += 16) {
        int t0 = tt * 16;
        HF8 af;
#pragma unroll
        for (int j = 0; j < 8; j++) af.h[j] = C[(fkg * 8 + j) * CSTR + t0 + fc];
        f32x4 acc0 = (f32x4){b1v[0], b1v[0], b1v[0], b1v[0]};
        f32x4 acc1 = (f32x4){b1v[1], b1v[1], b1v[1], b1v[1]};
        acc0 = __builtin_amdgcn_mfma_f32_16x16x32_f16(af.v, w1f[0].v, acc0, 0, 0, 0);
        acc1 = __builtin_amdgcn_mfma_f32_16x16x32_f16(af.v, w1f[1].v, acc1, 0, 0, 0);
#pragma unroll
        for (int j2 = 0; j2 < 4; j2++) {
            int p = fkg * 4 + j2;
            float h0 = acc0[j2]; h0 = h0 * sigm(h0);
            float h1 = acc1[j2]; h1 = h1 * sigm(h1);
            hmb[p * 36 + fc] = (f16)h0;
            hmb[p * 36 + 16 + fc] = (f16)h1;
        }
        HF8 hf;
        hf.u2[0] = *(const uint2*)&hmb[fc * 36 + fkg * 8];
        hf.u2[1] = *(const uint2*)&hmb[fc * 36 + fkg * 8 + 4];
        f32x4 acc2 = (f32x4){b2v, b2v, b2v, b2v};
        acc2 = __builtin_amdgcn_mfma_f32_16x16x32_f16(hf.v, w2f.v, acc2, 0, 0, 0);
#pragma unroll
        for (int j2 = 0; j2 < 4; j2 += 2) {
            uint_t* pp = (uint_t*)&C[fc * CSTR + t0 + fkg * 4 + j2];
            U1H2 old, neu;
            old.u = *pp;
            neu.h[0] = (f16)((float)old.h[0] + acc2[j2]);
            neu.h[1] = (f16)((float)old.h[1] + acc2[j2 + 1]);
            *pp = neu.u;
        }
    }
    __syncthreads();

    {
        const f16* row = &C[wv * CSTR];
        float vals[32];
        float m = -1e30f;
#pragma unroll
        for (int c = 0; c < 4; c++) {
            HF8 sv;
            sv.u4 = *(const uint4*)&row[c * 512 + lane * 8];
#pragma unroll
            for (int e = 0; e < 8; e++) {
                vals[c * 8 + e] = (float)sv.h[e];
                m = fmaxf(m, vals[c * 8 + e]);
            }
        }
#pragma unroll
        for (int d = 1; d < 64; d <<= 1) m = fmaxf(m, __shfl_xor(m, d, 64));
        float s = 0.0f;
#pragma unroll
        for (int c = 0; c < 32; c++) {
            vals[c] = __expf(vals[c] - m);
            s += vals[c];
        }
#pragma unroll
        for (int d = 1; d < 64; d <<= 1) s += __shfl_xor(s, d, 64);
        float ri = __builtin_amdgcn_rcpf(s);
        f16* dst = sc + ((size_t)wv * CHUNK + r) * SEQ;
#pragma unroll
        for (int c = 0; c < 4; c++) {
            HF8 po;
#pragma unroll
            for (int e = 0; e < 8; e++) po.h[e] = (f16)(vals[c * 8 + e] * ri);
            *(uint4*)&dst[c * 512 + lane * 8] = po.u4;
        }
    }
}

// ---------------- f16 MFMA PV ----------------
__global__ __launch_bounds__(256) void pvm_k(const f16* __restrict__ scP,
                                             const ushort_t* __restrict__ vt,
                                             f16* __restrict__ aob, int cb) {
    int h = blockIdx.y;
    int s0 = blockIdx.x * 32;
    __shared__ f16 P[32][72];
    __shared__ f16 Vt[64][72];
    int tid = threadIdx.x;
    int lane = tid & 63, wave = tid >> 6;
    int wr = (wave >> 1) * 16, wc = (wave & 1) * 32;
    f32x4 acc[2];
    acc[0] = (f32x4){0.f, 0.f, 0.f, 0.f};
    acc[1] = (f32x4){0.f, 0.f, 0.f, 0.f};
    int pr = tid >> 3, pc = (tid & 7) * 8;
    int vr = tid >> 2, vc = (tid & 3) * 16;
    for (int t0 = 0; t0 < SEQ; t0 += 64) {
        {
            *(uint4*)&P[pr][pc] =
                *(const uint4*)(scP + ((size_t)h * CHUNK + s0 + pr) * SEQ + t0 + pc);
            const ushort_t* vp = vt + ((size_t)h * 64 + vr) * SEQ + t0 + vc;
            *(uint4*)&Vt[vr][vc] = *(const uint4*)vp;
            *(uint4*)&Vt[vr][vc + 8] = *(const uint4*)(vp + 8);
        }
        __syncthreads();
#pragma unroll
        for (int ks = 0; ks < 2; ks++) {
            int kof = ks * 32 + (lane >> 4) * 8;
            f16x8 pa = *(const f16x8*)&P[wr + (lane & 15)][kof];
#pragma unroll
            for (int n = 0; n < 2; n++) {
                f16x8 vb = *(const f16x8*)&Vt[wc + n * 16 + (lane & 15)][kof];
                acc[n] = __builtin_amdgcn_mfma_f32_16x16x32_f16(pa, vb, acc[n], 0, 0, 0);
            }
        }
        __syncthreads();
    }
#pragma unroll
    for (int j = 0; j < 4; j++) {
        int s = cb + s0 + wr + (lane >> 4) * 4 + j;
#pragma unroll
        for (int n = 0; n < 2; n++) {
            int d = h * 64 + wc + n * 16 + (lane & 15);
            aob[(size_t)s * DMODEL + d] = (f16)acc[n][j];
        }
    }
}

extern "C" void kernel_launch(void* const* d_in, const int* in_sizes, int n_in,
                              void* d_out, int out_size, void* d_ws, size_t ws_size,
                              hipStream_t stream) {
    const float* x = (const float*)d_in[0];
    const float* wq = (const float*)d_in[1];
    const float* wk = (const float*)d_in[2];
    const float* wv = (const float*)d_in[3];
    const float* wo = (const float*)d_in[4];
    const float* pos_emb = (const float*)d_in[5];
    const float* mlp_w1 = (const float*)d_in[6];
    const float* mlp_b1 = (const float*)d_in[7];
    const float* mlp_w2 = (const float*)d_in[8];
    const float* mlp_b2 = (const float*)d_in[9];
    const float* ffn_w1 = (const float*)d_in[10];
    const float* ffn_w2 = (const float*)d_in[11];
    const float* ffn_w3 = (const float*)d_in[12];
    const float* attn_norm_w = (const float*)d_in[13];
    const float* ffn_norm_w = (const float*)d_in[14];
    float* out = (float*)d_out;

    char* ws = (char*)d_ws;
    const size_t MB = 1024 * 1024;
    f16* nxb = (f16*)(ws + 0);               // 0-4
    f16* qf = (f16*)(ws + 4 * MB);           // 4-8   (phase C: nxb2)
    f16* kf = (f16*)(ws + 8 * MB);           // 8-12  (phase C: g1b 8-24)
    f16* vb = (f16*)(ws + 12 * MB);          // 12-16
    f16* vt = (f16*)(ws + 16 * MB);          // 16-20
    f16* li = (f16*)(ws + 20 * MB);          // 20-28
    f16* aob = (f16*)(ws + 28 * MB);         // 28-32
    float* x1 = (float*)(ws + 32 * MB);      // 32-40
    f16* wqkvt = (f16*)(ws + 40 * MB);       // 40-46 (phase 1)
    f16* sc = (f16*)(ws + 40 * MB);          // 40-104 (phase 2, CHUNK=1024)
    f16* wot = (f16*)(ws + 40 * MB);         // 40-42 (phase B)
    f16* w13t = (f16*)(ws + 40 * MB);        // 40-56 (phase C, interleaved)
    f16* w2t = (f16*)(ws + 56 * MB);         // 56-64
    f16* nxb2 = (f16*)(ws + 4 * MB);
    f16* g1b = (f16*)(ws + 8 * MB);          // 8-24

    // ---- phase 1: norm + fused QKV (64-tile, 1536 blocks) ----
    transconv3_k<<<dim3(DMODEL / 64, DMODEL / 64, 3), 256, 0, stream>>>(wq, wk, wv, wqkvt);
    rmsnormf_k<<<SEQ, 256, 0, stream>>>(x, attn_norm_w, nxb);
    gemm64_k<<<dim3(3 * DMODEL / 64, SEQ / 64), 256, 0, stream>>>(
        nxb, wqkvt, nullptr, qf, SEQ, 3 * DMODEL, DMODEL, 2, kf, vb);
    copelogits_k<<<SEQ, 256, 0, stream>>>(qf, pos_emb, li);
    tv_k<<<dim3(SEQ / 64, NH), 256, 0, stream>>>((const ushort_t*)vb, (ushort_t*)vt);

    // ---- phase 2: attention chunks ----
    for (int ch = 0; ch < NCH; ch++) {
        int cb = ch * CHUNK;
        scoresm_k<<<dim3(SEQ / 128, CHUNK / 128, NH), 256, 0, stream>>>(qf, kf, sc, cb);
        cope_k<<<CHUNK, 1024, 0, stream>>>(sc, li, mlp_w1, mlp_b1, mlp_w2, mlp_b2, cb);
        pvm_k<<<dim3(CHUNK / 32, NH), 256, 0, stream>>>(sc, (const ushort_t*)vt, aob, cb);
    }

    // ---- phase B: out @ wo + x (64-tile, 512 blocks) ----
    transconv_k<<<dim3(DMODEL / 64, DMODEL / 64), 256, 0, stream>>>(wo, wot, DMODEL, DMODEL);
    gemm64_k<<<dim3(DMODEL / 64, SEQ / 64), 256, 0, stream>>>(
        aob, wot, x, x1, SEQ, DMODEL, DMODEL, 0, nullptr, nullptr);

    // ---- phase C: FFN ----
    rmsnormf_k<<<SEQ, 256, 0, stream>>>(x1, ffn_norm_w, nxb2);
    transconv2_k<<<dim3(FFDIM / 64, DMODEL / 64), 256, 0, stream>>>(ffn_w1, ffn_w3, w13t, DMODEL, FFDIM);
    transconv_k<<<dim3(DMODEL / 64, FFDIM / 64), 256, 0, stream>>>(ffn_w2, w2t, FFDIM, DMODEL);
    gemm128_k<<<dim3(2 * FFDIM / 128, SEQ / 128), 256, 0, stream>>>(
        nxb2, w13t, nullptr, g1b, SEQ, 2 * FFDIM, DMODEL, 4);
    gemm64_k<<<dim3(DMODEL / 64, SEQ / 64), 256, 0, stream>>>(
        g1b, w2t, x1, out, SEQ, DMODEL, FFDIM, 0, nullptr, nullptr);
}

// Round 19
// 425.167 us; speedup vs baseline: 1.0379x; 1.0304x over previous
//
#include <hip/hip_runtime.h>
#include <hip/hip_bf16.h>
#include <hip/hip_fp16.h>
#include <math.h>

#define SEQ 2048
#define DMODEL 1024
#define NH 16
#define DHEAD 64
#define FFDIM 4096
#define NPOSE 128
#define MLPWID 32
#define EPSV 1e-5f
#define CHUNK 1024
#define NCH (SEQ / CHUNK)

typedef unsigned short ushort_t;
typedef unsigned int uint_t;
typedef _Float16 f16;
typedef __attribute__((ext_vector_type(8))) _Float16 f16x8;
typedef __attribute__((ext_vector_type(4))) float f32x4;

union HF8 { f16x8 v; f16 h[8]; ushort_t s[8]; uint2 u2[2]; uint4 u4; };
union U1H2 { uint_t u; f16 h[2]; };
union U2H4 { uint2 u; f16 h[4]; };

__device__ __forceinline__ float sigm(float x) {
    return __builtin_amdgcn_rcpf(1.0f + __expf(-x));
}
__device__ __forceinline__ void gl_lds16(const void* g, void* l) {
    __builtin_amdgcn_global_load_lds((const __attribute__((address_space(1))) uint_t*)g,
                                     (__attribute__((address_space(3))) uint_t*)l, 16, 0, 0);
}

// ---------------- RMSNorm, f16 out ----------------
__global__ __launch_bounds__(256) void rmsnormf_k(const float* __restrict__ x,
                                                  const float* __restrict__ w,
                                                  f16* __restrict__ o) {
    int row = blockIdx.x;
    int tid = threadIdx.x;
    const float4* xr = (const float4*)(x + (size_t)row * DMODEL);
    float4 v = xr[tid];
    float ss = v.x * v.x + v.y * v.y + v.z * v.z + v.w * v.w;
#pragma unroll
    for (int d = 1; d < 64; d <<= 1) ss += __shfl_xor(ss, d, 64);
    __shared__ float red[4];
    int lane = tid & 63, wv = tid >> 6;
    if (lane == 0) red[wv] = ss;
    __syncthreads();
    float tot = red[0] + red[1] + red[2] + red[3];
    float r = rsqrtf(tot / (float)DMODEL + EPSV);
    const float4* wr = (const float4*)w;
    float4 wv4 = wr[tid];
    U2H4 ob;
    ob.h[0] = (f16)(v.x * r * wv4.x);
    ob.h[1] = (f16)(v.y * r * wv4.y);
    ob.h[2] = (f16)(v.z * r * wv4.z);
    ob.h[3] = (f16)(v.w * r * wv4.w);
    ((uint2*)(o + (size_t)row * DMODEL))[tid] = ob.u;
}

// ---------------- V transpose ----------------
__global__ __launch_bounds__(256) void tv_k(const ushort_t* __restrict__ vb,
                                            ushort_t* __restrict__ vt) {
    int h = blockIdx.y, t0 = blockIdx.x * 64;
    __shared__ ushort_t T[64][76];
    int tid = threadIdx.x;
#pragma unroll
    for (int it = 0; it < 2; it++) {
        int a = tid + it * 256;
        int t = a >> 3, c8 = (a & 7) * 8;
        HF8 v;
        v.u4 = *(const uint4*)(vb + (size_t)(t0 + t) * DMODEL + h * 64 + c8);
#pragma unroll
        for (int j = 0; j < 8; j++) T[c8 + j][t] = v.s[j];
    }
    __syncthreads();
#pragma unroll
    for (int it = 0; it < 2; it++) {
        int a = tid + it * 256;
        int d = a >> 3, c8 = (a & 7) * 8;
        HF8 o;
#pragma unroll
        for (int j = 0; j < 8; j++) o.s[j] = T[d][c8 + j];
        *(uint4*)(vt + ((size_t)h * 64 + d) * SEQ + t0 + c8) = o.u4;
    }
}

// ---------------- weight transpose+convert: f32[K][N] -> f16[N][K] ----------------
__global__ __launch_bounds__(256) void transconv_k(const float* __restrict__ in,
                                                   f16* __restrict__ out,
                                                   int K, int N) {
    __shared__ f16 T[64][72];
    int k0 = blockIdx.y * 64, n0 = blockIdx.x * 64;
    int tid = threadIdx.x;
    int r = tid >> 4, c4 = (tid & 15) * 4;
#pragma unroll
    for (int i = 0; i < 4; i++) {
        float4 v = *(const float4*)(in + (size_t)(k0 + r + i * 16) * N + n0 + c4);
        T[c4 + 0][r + i * 16] = (f16)v.x;
        T[c4 + 1][r + i * 16] = (f16)v.y;
        T[c4 + 2][r + i * 16] = (f16)v.z;
        T[c4 + 3][r + i * 16] = (f16)v.w;
    }
    __syncthreads();
    int n = tid >> 2, kk = (tid & 3) * 16;
    uint4* dst = (uint4*)(out + (size_t)(n0 + n) * K + k0 + kk);
    dst[0] = *(const uint4*)&T[n][kk];
    dst[1] = *(const uint4*)&T[n][kk + 8];
}

// ---------------- 3-way weight transpose (QKV) via blockIdx.z ----------------
__global__ __launch_bounds__(256) void transconv3_k(const float* __restrict__ w0,
                                                    const float* __restrict__ w1p,
                                                    const float* __restrict__ w2p,
                                                    f16* __restrict__ out) {
    const int K = DMODEL, N = DMODEL;
    const float* in = (blockIdx.z == 0) ? w0 : (blockIdx.z == 1) ? w1p : w2p;
    f16* o = out + (size_t)blockIdx.z * DMODEL * DMODEL;
    __shared__ f16 T[64][72];
    int k0 = blockIdx.y * 64, n0 = blockIdx.x * 64;
    int tid = threadIdx.x;
    int r = tid >> 4, c4 = (tid & 15) * 4;
#pragma unroll
    for (int i = 0; i < 4; i++) {
        float4 v = *(const float4*)(in + (size_t)(k0 + r + i * 16) * N + n0 + c4);
        T[c4 + 0][r + i * 16] = (f16)v.x;
        T[c4 + 1][r + i * 16] = (f16)v.y;
        T[c4 + 2][r + i * 16] = (f16)v.z;
        T[c4 + 3][r + i * 16] = (f16)v.w;
    }
    __syncthreads();
    int n = tid >> 2, kk = (tid & 3) * 16;
    uint4* dst = (uint4*)(o + (size_t)(n0 + n) * K + k0 + kk);
    dst[0] = *(const uint4*)&T[n][kk];
    dst[1] = *(const uint4*)&T[n][kk + 8];
}

// ---------------- w1/w3 transpose+convert, row-interleaved ----------------
__global__ __launch_bounds__(256) void transconv2_k(const float* __restrict__ w1,
                                                    const float* __restrict__ w3,
                                                    f16* __restrict__ out,
                                                    int K, int N) {
    __shared__ f16 T[64][72];
    int k0 = blockIdx.y * 64, n0 = blockIdx.x * 64;
    int tid = threadIdx.x;
    int r = tid >> 4, c4 = (tid & 15) * 4;
    int n = tid >> 2, kk = (tid & 3) * 16;
#pragma unroll
    for (int half = 0; half < 2; half++) {
        const float* in = half ? w3 : w1;
#pragma unroll
        for (int i = 0; i < 4; i++) {
            float4 v = *(const float4*)(in + (size_t)(k0 + r + i * 16) * N + n0 + c4);
            T[c4 + 0][r + i * 16] = (f16)v.x;
            T[c4 + 1][r + i * 16] = (f16)v.y;
            T[c4 + 2][r + i * 16] = (f16)v.z;
            T[c4 + 3][r + i * 16] = (f16)v.w;
        }
        __syncthreads();
        int gc = n0 + n;
        int rp = (gc >> 4) * 32 + (gc & 15) + half * 16;
        uint4* dst = (uint4*)(out + (size_t)rp * K + k0 + kk);
        dst[0] = *(const uint4*)&T[n][kk];
        dst[1] = *(const uint4*)&T[n][kk + 8];
        __syncthreads();
    }
}

// ---------------- f16 MFMA GEMM 128x128 (TN), BK=64, XOR-swizzled LDS, XCD-swizzled ----------------
// mode 0: f32 out (+add). mode 1: f16 out. mode 4: w1w3-interleaved silu-mul.
// LDS [128][64] f16; content at [row][g] = G[row][g ^ (row&7)] (8-f16 groups);
// linear gl_lds dest + pre-swizzled global source + swizzled ds_read (m201 pattern).
__global__ __launch_bounds__(256) void gemm128_k(const f16* __restrict__ A,
                                                 const f16* __restrict__ Bt,
                                                 const float* __restrict__ add,
                                                 void* __restrict__ Cout,
                                                 int M, int N, int K, int mode) {
    __shared__ f16 Al[128 * 64];
    __shared__ f16 Bl[128 * 64];
    int tid = threadIdx.x;
    int lane = tid & 63, wave = tid >> 6;
    int gx = gridDim.x, gy = gridDim.y;
    int nwg = gx * gy;
    int bx = blockIdx.x, by = blockIdx.y;
    if ((nwg & 7) == 0) {
        int flat = by * gx + bx;
        int cpx = nwg >> 3;
        int l = (flat & 7) * cpx + (flat >> 3);
        bx = l / gy;
        by = l % gy;
    }
    int brow = by * 128, bcol = bx * 128;
    int wr = (wave >> 1) * 64, wc = (wave & 1) * 64;
    f32x4 acc[4][4];
#pragma unroll
    for (int m = 0; m < 4; m++)
#pragma unroll
        for (int n = 0; n < 4; n++) acc[m][n] = (f32x4){0.f, 0.f, 0.f, 0.f};

    // staging: row = tid>>3 (+32 per call), source col-group pre-swizzled by row&7
    int srow = tid >> 3;
    int scol = (((tid & 7) ^ (srow & 7)) * 8);
    const f16* Ag = A + (size_t)(brow + srow) * K + scol;
    const f16* Bg = Bt + (size_t)(bcol + srow) * K + scol;
    f16* Ald = &Al[wave * 512];
    f16* Bld = &Bl[wave * 512];
    size_t rstep32 = (size_t)32 * K;

    for (int k0 = 0; k0 < K; k0 += 64) {
#pragma unroll
        for (int i = 0; i < 4; i++) {
            gl_lds16(Ag + i * rstep32 + k0, Ald + i * 2048);
            gl_lds16(Bg + i * rstep32 + k0, Bld + i * 2048);
        }
        __syncthreads();
#pragma unroll
        for (int ks = 0; ks < 2; ks++) {
            f16x8 af[4], bfr[4];
            int gbase = ks * 4 + (lane >> 4);   // k-group 0..7 within BK=64
#pragma unroll
            for (int m = 0; m < 4; m++) {
                int r = wr + m * 16 + (lane & 15);
                af[m] = *(const f16x8*)&Al[r * 64 + ((gbase ^ (r & 7)) * 8)];
            }
#pragma unroll
            for (int n = 0; n < 4; n++) {
                int r = wc + n * 16 + (lane & 15);
                bfr[n] = *(const f16x8*)&Bl[r * 64 + ((gbase ^ (r & 7)) * 8)];
            }
#pragma unroll
            for (int m = 0; m < 4; m++)
#pragma unroll
                for (int n = 0; n < 4; n++)
                    acc[m][n] = __builtin_amdgcn_mfma_f32_16x16x32_f16(af[m], bfr[n], acc[m][n], 0, 0, 0);
        }
        __syncthreads();
    }
    int crow0 = brow + wr + (lane >> 4) * 4;
    int ccol = bcol + wc + (lane & 15);
#pragma unroll
    for (int m = 0; m < 4; m++)
#pragma unroll
        for (int j = 0; j < 4; j++) {
            int row = crow0 + m * 16 + j;
            if (mode == 4) {
#pragma unroll
                for (int n = 0; n < 4; n += 2) {
                    int c = ccol + n * 16;
                    int colOut = (c >> 5) * 16 + (c & 15);
                    float v1 = acc[m][n][j];
                    float v3 = acc[m][n + 1][j];
                    ((f16*)Cout)[(size_t)row * (N / 2) + colOut] =
                        (f16)(v1 * sigm(v1) * v3);
                }
            } else {
#pragma unroll
                for (int n = 0; n < 4; n++) {
                    int col = ccol + n * 16;
                    float v = acc[m][n][j];
                    if (mode == 0) {
                        if (add) v += add[(size_t)row * N + col];
                        ((float*)Cout)[(size_t)row * N + col] = v;
                    } else {
                        ((f16*)Cout)[(size_t)row * N + col] = (f16)v;
                    }
                }
            }
        }
}

// ---------------- f16 MFMA GEMM 64x64 (TN), XCD-swizzled ----------------
// mode 0: f32 out (+add). mode 1: f16. mode 2: qkv split (Cout=q, p2=k, p3=v).
__global__ __launch_bounds__(256) void gemm64_k(const f16* __restrict__ A,
                                                const f16* __restrict__ Bt,
                                                const float* __restrict__ add,
                                                void* __restrict__ Cout,
                                                int M, int N, int K, int mode,
                                                f16* __restrict__ p2,
                                                f16* __restrict__ p3) {
    __shared__ f16 Al[64 * 32];
    __shared__ f16 Bl[64 * 32];
    int tid = threadIdx.x;
    int lane = tid & 63, wave = tid >> 6;
    int gx = gridDim.x, gy = gridDim.y;
    int nwg = gx * gy;
    int bx = blockIdx.x, by = blockIdx.y;
    if ((nwg & 7) == 0) {
        int flat = by * gx + bx;
        int cpx = nwg >> 3;
        int l = (flat & 7) * cpx + (flat >> 3);
        bx = l / gy;
        by = l % gy;
    }
    int brow = by * 64, bcol = bx * 64;
    int wr = (wave >> 1) * 32, wc = (wave & 1) * 32;
    f32x4 acc[2][2];
#pragma unroll
    for (int m = 0; m < 2; m++)
#pragma unroll
        for (int n = 0; n < 2; n++) acc[m][n] = (f32x4){0.f, 0.f, 0.f, 0.f};

    const f16* Ag = A + (size_t)(brow + (tid >> 2)) * K + (tid & 3) * 8;
    const f16* Bg = Bt + (size_t)(bcol + (tid >> 2)) * K + (tid & 3) * 8;
    f16* Ald = &Al[wave * 512];
    f16* Bld = &Bl[wave * 512];

    for (int k0 = 0; k0 < K; k0 += 32) {
        gl_lds16(Ag + k0, Ald);
        gl_lds16(Bg + k0, Bld);
        __syncthreads();
        f16x8 af[2], bfr[2];
        int kof = (lane >> 4) * 8;
#pragma unroll
        for (int m = 0; m < 2; m++)
            af[m] = *(const f16x8*)&Al[(wr + m * 16 + (lane & 15)) * 32 + kof];
#pragma unroll
        for (int n = 0; n < 2; n++)
            bfr[n] = *(const f16x8*)&Bl[(wc + n * 16 + (lane & 15)) * 32 + kof];
#pragma unroll
        for (int m = 0; m < 2; m++)
#pragma unroll
            for (int n = 0; n < 2; n++)
                acc[m][n] = __builtin_amdgcn_mfma_f32_16x16x32_f16(af[m], bfr[n], acc[m][n], 0, 0, 0);
        __syncthreads();
    }
    int crow0 = brow + wr + (lane >> 4) * 4;
    int ccol = bcol + wc + (lane & 15);
#pragma unroll
    for (int m = 0; m < 2; m++)
#pragma unroll
        for (int j = 0; j < 4; j++) {
            int row = crow0 + m * 16 + j;
#pragma unroll
            for (int n = 0; n < 2; n++) {
                int col = ccol + n * 16;
                float v = acc[m][n][j];
                if (mode == 0) {
                    if (add) v += add[(size_t)row * N + col];
                    ((float*)Cout)[(size_t)row * N + col] = v;
                } else if (mode == 1) {
                    ((f16*)Cout)[(size_t)row * N + col] = (f16)v;
                } else {
                    size_t o = (size_t)row * DMODEL;
                    if (col < DMODEL) ((f16*)Cout)[o + col] = (f16)v;
                    else if (col < 2 * DMODEL) p2[o + col - DMODEL] = (f16)v;
                    else p3[o + col - 2 * DMODEL] = (f16)v;
                }
            }
        }
}

// ---------------- MFMA scores, 128x128 tile ----------------
__global__ __launch_bounds__(256) void scoresm_k(const f16* __restrict__ qf,
                                                 const f16* __restrict__ kf,
                                                 f16* __restrict__ sc, int cb) {
    int h = blockIdx.z;
    int il0 = blockIdx.y * 128;
    int j0 = blockIdx.x * 128;
    __shared__ f16 Qf[128][72];
    __shared__ f16 Kf[128][72];
    int tid = threadIdx.x;
#pragma unroll
    for (int i = 0; i < 4; i++) {
        int row = i * 32 + (tid >> 3);
        int c8 = (tid & 7) * 8;
        *(uint4*)&Qf[row][c8] =
            *(const uint4*)(qf + (size_t)(cb + il0 + row) * DMODEL + h * 64 + c8);
        *(uint4*)&Kf[row][c8] =
            *(const uint4*)(kf + (size_t)(j0 + row) * DMODEL + h * 64 + c8);
    }
    __syncthreads();
    int lane = tid & 63, wave = tid >> 6;
    int wr = (wave >> 1) * 64, wc = (wave & 1) * 64;
    f32x4 acc[4][4];
#pragma unroll
    for (int m = 0; m < 4; m++)
#pragma unroll
        for (int n = 0; n < 4; n++) acc[m][n] = (f32x4){0.f, 0.f, 0.f, 0.f};
#pragma unroll
    for (int ks = 0; ks < 2; ks++) {
        int kof = ks * 32 + (lane >> 4) * 8;
        f16x8 aQ[4], bK[4];
#pragma unroll
        for (int m = 0; m < 4; m++)
            aQ[m] = *(const f16x8*)&Qf[wr + m * 16 + (lane & 15)][kof];
#pragma unroll
        for (int n = 0; n < 4; n++)
            bK[n] = *(const f16x8*)&Kf[wc + n * 16 + (lane & 15)][kof];
#pragma unroll
        for (int m = 0; m < 4; m++)
#pragma unroll
            for (int n = 0; n < 4; n++)
                acc[m][n] = __builtin_amdgcn_mfma_f32_16x16x32_f16(aQ[m], bK[n], acc[m][n], 0, 0, 0);
    }
#pragma unroll
    for (int m = 0; m < 4; m++)
#pragma unroll
        for (int j = 0; j < 4; j++) {
            int il = il0 + wr + m * 16 + (lane >> 4) * 4 + j;
#pragma unroll
            for (int n = 0; n < 4; n++) {
                int jj = j0 + wc + n * 16 + (lane & 15);
                sc[((size_t)h * CHUNK + il) * SEQ + jj] = (f16)(acc[m][n][j] * 0.125f);
            }
        }
}

// ---------------- logits_int -> f16 ----------------
__global__ __launch_bounds__(256) void copelogits_k(const f16* __restrict__ qf,
                                                    const float* __restrict__ pe,
                                                    f16* __restrict__ li) {
    int s1 = blockIdx.x;
    int tid = threadIdx.x;
    __shared__ float PE[DHEAD * NPOSE];
    __shared__ float QR[DMODEL];
    for (int i = tid; i < DHEAD * NPOSE; i += 256) PE[i] = pe[i];
    for (int i = tid; i < DMODEL; i += 256) QR[i] = (float)qf[(size_t)s1 * DMODEL + i];
    __syncthreads();
#pragma unroll
    for (int j = 0; j < 8; j++) {
        int o = j * 256 + tid;
        int h = o >> 7, n = o & 127;
        const float* qhp = &QR[h * DHEAD];
        float acc = 0.0f;
#pragma unroll 8
        for (int d = 0; d < DHEAD; d++) acc += qhp[d] * PE[d * NPOSE + n];
        li[(size_t)s1 * (NH * NPOSE) + o] = (f16)acc;
    }
}

// ---------------- fused CoPE: ILP scan + bias + f16 MFMA MLP + softmax -> P ----------------
#define CSTR 2052
__global__ __launch_bounds__(1024, 1) void cope_k(f16* __restrict__ sc,
                                                  const f16* __restrict__ li,
                                                  const float* __restrict__ w1,
                                                  const float* __restrict__ b1,
                                                  const float* __restrict__ w2,
                                                  const float* __restrict__ b2,
                                                  int cb) {
    __shared__ f16 C[32 * CSTR];
    __shared__ uint_t Lif2[NH * 130];
    __shared__ f16 HMB[16][16 * 36];
    int r = blockIdx.x;
    int tid = threadIdx.x;
    int lane = tid & 63, wv = tid >> 6;

    const f16* srow = sc + ((size_t)wv * CHUNK + r) * SEQ;
    HF8 rv[4];
#pragma unroll
    for (int c = 0; c < 4; c++) rv[c].u4 = *(const uint4*)&srow[c * 512 + lane * 8];

    {
        const f16* lh = li + (size_t)(cb + r) * (NH * NPOSE) + wv * NPOSE;
#pragma unroll
        for (int e = 0; e < 2; e++) {
            int n = lane + e * 64;
            U1H2 pk;
            pk.h[0] = lh[n];
            pk.h[1] = lh[(n < NPOSE - 1) ? n + 1 : NPOSE - 1];
            Lif2[wv * 130 + n] = pk.u;
        }
    }

    {
        f16* crow = &C[wv * CSTR];
        f16* brow = &C[(16 + wv) * CSTR];
        const uint_t* lrow = &Lif2[wv * 130];
        float g[4][8];
        float S[4];
#pragma unroll
        for (int c = 0; c < 4; c++) {
            HF8 sv = rv[c];
            float s = 0.0f;
#pragma unroll
            for (int e = 0; e < 8; e++) {
                g[c][e] = sigm((float)sv.h[e]);
                s += g[c][e];
            }
            S[c] = s;
        }
#pragma unroll
        for (int dd = 1; dd < 64; dd <<= 1) {
#pragma unroll
            for (int c = 0; c < 4; c++) {
                float o = __shfl_down(S[c], dd, 64);
                S[c] = (lane + dd < 64) ? S[c] + o : S[c];
            }
        }
        float tot[4];
#pragma unroll
        for (int c = 0; c < 4; c++) tot[c] = __shfl(S[c], 0, 64);
        float carry[4];
        carry[3] = 0.0f;
        carry[2] = tot[3];
        carry[1] = tot[3] + tot[2];
        carry[0] = carry[1] + tot[1];
#pragma unroll
        for (int c = 0; c < 4; c++) {
            float p = S[c] + carry[c];
            HF8 bo;
#pragma unroll
            for (int e = 0; e < 8; e++) {
                float pos = fminf(p, 127.0f);
                int fl = (int)pos;
                float fr = pos - (float)fl;
                U1H2 lv;
                lv.u = lrow[fl];
                float lf = (float)lv.h[0];
                bo.h[e] = (f16)(lf + ((float)lv.h[1] - lf) * fr);
                p -= g[c][e];
            }
            int t = c * 512 + lane * 8;
            *(uint4*)&crow[t] = rv[c].u4;
            *(uint4*)&brow[t] = bo.u4;
        }
    }
    __syncthreads();

    int fkg = lane >> 4;
    int fc = lane & 15;
    HF8 w1f[2], w2f;
    float b1v[2], b2v;
#pragma unroll
    for (int half = 0; half < 2; half++) {
#pragma unroll
        for (int j = 0; j < 8; j++)
            w1f[half].h[j] = (f16)w1[(fkg * 8 + j) * MLPWID + half * 16 + fc];
        b1v[half] = b1[half * 16 + fc];
    }
#pragma unroll
    for (int j = 0; j < 8; j++) w2f.h[j] = (f16)w2[(fkg * 8 + j) * NH + fc];
    b2v = b2[fc];

    f16* hmb = HMB[wv];
#pragma unroll 2
    for (int tt = wv; tt < SEQ / 16; tt += 16) {
        int t0 = tt * 16;
        HF8 af;
#pragma unroll
        for (int j = 0; j < 8; j++) af.h[j] = C[(fkg * 8 + j) * CSTR + t0 + fc];
        f32x4 acc0 = (f32x4){b1v[0], b1v[0], b1v[0], b1v[0]};
        f32x4 acc1 = (f32x4){b1v[1], b1v[1], b1v[1], b1v[1]};
        acc0 = __builtin_amdgcn_mfma_f32_16x16x32_f16(af.v, w1f[0].v, acc0, 0, 0, 0);
        acc1 = __builtin_amdgcn_mfma_f32_16x16x32_f16(af.v, w1f[1].v, acc1, 0, 0, 0);
#pragma unroll
        for (int j2 = 0; j2 < 4; j2++) {
            int p = fkg * 4 + j2;
            float h0 = acc0[j2]; h0 = h0 * sigm(h0);
            float h1 = acc1[j2]; h1 = h1 * sigm(h1);
            hmb[p * 36 + fc] = (f16)h0;
            hmb[p * 36 + 16 + fc] = (f16)h1;
        }
        HF8 hf;
        hf.u2[0] = *(const uint2*)&hmb[fc * 36 + fkg * 8];
        hf.u2[1] = *(const uint2*)&hmb[fc * 36 + fkg * 8 + 4];
        f32x4 acc2 = (f32x4){b2v, b2v, b2v, b2v};
        acc2 = __builtin_amdgcn_mfma_f32_16x16x32_f16(hf.v, w2f.v, acc2, 0, 0, 0);
#pragma unroll
        for (int j2 = 0; j2 < 4; j2 += 2) {
            uint_t* pp = (uint_t*)&C[fc * CSTR + t0 + fkg * 4 + j2];
            U1H2 old, neu;
            old.u = *pp;
            neu.h[0] = (f16)((float)old.h[0] + acc2[j2]);
            neu.h[1] = (f16)((float)old.h[1] + acc2[j2 + 1]);
            *pp = neu.u;
        }
    }
    __syncthreads();

    {
        const f16* row = &C[wv * CSTR];
        float vals[32];
        float m = -1e30f;
#pragma unroll
        for (int c = 0; c < 4; c++) {
            HF8 sv;
            sv.u4 = *(const uint4*)&row[c * 512 + lane * 8];
#pragma unroll
            for (int e = 0; e < 8; e++) {
                vals[c * 8 + e] = (float)sv.h[e];
                m = fmaxf(m, vals[c * 8 + e]);
            }
        }
#pragma unroll
        for (int d = 1; d < 64; d <<= 1) m = fmaxf(m, __shfl_xor(m, d, 64));
        float s = 0.0f;
#pragma unroll
        for (int c = 0; c < 32; c++) {
            vals[c] = __expf(vals[c] - m);
            s += vals[c];
        }
#pragma unroll
        for (int d = 1; d < 64; d <<= 1) s += __shfl_xor(s, d, 64);
        float ri = __builtin_amdgcn_rcpf(s);
        f16* dst = sc + ((size_t)wv * CHUNK + r) * SEQ;
#pragma unroll
        for (int c = 0; c < 4; c++) {
            HF8 po;
#pragma unroll
            for (int e = 0; e < 8; e++) po.h[e] = (f16)(vals[c * 8 + e] * ri);
            *(uint4*)&dst[c * 512 + lane * 8] = po.u4;
        }
    }
}

// ---------------- f16 MFMA PV ----------------
__global__ __launch_bounds__(256) void pvm_k(const f16* __restrict__ scP,
                                             const ushort_t* __restrict__ vt,
                                             f16* __restrict__ aob, int cb) {
    int h = blockIdx.y;
    int s0 = blockIdx.x * 32;
    __shared__ f16 P[32][72];
    __shared__ f16 Vt[64][72];
    int tid = threadIdx.x;
    int lane = tid & 63, wave = tid >> 6;
    int wr = (wave >> 1) * 16, wc = (wave & 1) * 32;
    f32x4 acc[2];
    acc[0] = (f32x4){0.f, 0.f, 0.f, 0.f};
    acc[1] = (f32x4){0.f, 0.f, 0.f, 0.f};
    int pr = tid >> 3, pc = (tid & 7) * 8;
    int vr = tid >> 2, vc = (tid & 3) * 16;
    for (int t0 = 0; t0 < SEQ; t0 += 64) {
        {
            *(uint4*)&P[pr][pc] =
                *(const uint4*)(scP + ((size_t)h * CHUNK + s0 + pr) * SEQ + t0 + pc);
            const ushort_t* vp = vt + ((size_t)h * 64 + vr) * SEQ + t0 + vc;
            *(uint4*)&Vt[vr][vc] = *(const uint4*)vp;
            *(uint4*)&Vt[vr][vc + 8] = *(const uint4*)(vp + 8);
        }
        __syncthreads();
#pragma unroll
        for (int ks = 0; ks < 2; ks++) {
            int kof = ks * 32 + (lane >> 4) * 8;
            f16x8 pa = *(const f16x8*)&P[wr + (lane & 15)][kof];
#pragma unroll
            for (int n = 0; n < 2; n++) {
                f16x8 vb = *(const f16x8*)&Vt[wc + n * 16 + (lane & 15)][kof];
                acc[n] = __builtin_amdgcn_mfma_f32_16x16x32_f16(pa, vb, acc[n], 0, 0, 0);
            }
        }
        __syncthreads();
    }
#pragma unroll
    for (int j = 0; j < 4; j++) {
        int s = cb + s0 + wr + (lane >> 4) * 4 + j;
#pragma unroll
        for (int n = 0; n < 2; n++) {
            int d = h * 64 + wc + n * 16 + (lane & 15);
            aob[(size_t)s * DMODEL + d] = (f16)acc[n][j];
        }
    }
}

extern "C" void kernel_launch(void* const* d_in, const int* in_sizes, int n_in,
                              void* d_out, int out_size, void* d_ws, size_t ws_size,
                              hipStream_t stream) {
    const float* x = (const float*)d_in[0];
    const float* wq = (const float*)d_in[1];
    const float* wk = (const float*)d_in[2];
    const float* wv = (const float*)d_in[3];
    const float* wo = (const float*)d_in[4];
    const float* pos_emb = (const float*)d_in[5];
    const float* mlp_w1 = (const float*)d_in[6];
    const float* mlp_b1 = (const float*)d_in[7];
    const float* mlp_w2 = (const float*)d_in[8];
    const float* mlp_b2 = (const float*)d_in[9];
    const float* ffn_w1 = (const float*)d_in[10];
    const float* ffn_w2 = (const float*)d_in[11];
    const float* ffn_w3 = (const float*)d_in[12];
    const float* attn_norm_w = (const float*)d_in[13];
    const float* ffn_norm_w = (const float*)d_in[14];
    float* out = (float*)d_out;

    char* ws = (char*)d_ws;
    const size_t MB = 1024 * 1024;
    f16* nxb = (f16*)(ws + 0);               // 0-4
    f16* qf = (f16*)(ws + 4 * MB);           // 4-8   (phase C: nxb2)
    f16* kf = (f16*)(ws + 8 * MB);           // 8-12  (phase C: g1b 8-24)
    f16* vb = (f16*)(ws + 12 * MB);          // 12-16
    f16* vt = (f16*)(ws + 16 * MB);          // 16-20
    f16* li = (f16*)(ws + 20 * MB);          // 20-28
    f16* aob = (f16*)(ws + 28 * MB);         // 28-32
    float* x1 = (float*)(ws + 32 * MB);      // 32-40
    f16* wqkvt = (f16*)(ws + 40 * MB);       // 40-46 (phase 1)
    f16* sc = (f16*)(ws + 40 * MB);          // 40-104 (phase 2, CHUNK=1024)
    f16* wot = (f16*)(ws + 40 * MB);         // 40-42 (phase B)
    f16* w13t = (f16*)(ws + 40 * MB);        // 40-56 (phase C, interleaved)
    f16* w2t = (f16*)(ws + 56 * MB);         // 56-64
    f16* nxb2 = (f16*)(ws + 4 * MB);
    f16* g1b = (f16*)(ws + 8 * MB);          // 8-24

    // ---- phase 1: norm + fused QKV (64-tile, 1536 blocks) ----
    transconv3_k<<<dim3(DMODEL / 64, DMODEL / 64, 3), 256, 0, stream>>>(wq, wk, wv, wqkvt);
    rmsnormf_k<<<SEQ, 256, 0, stream>>>(x, attn_norm_w, nxb);
    gemm64_k<<<dim3(3 * DMODEL / 64, SEQ / 64), 256, 0, stream>>>(
        nxb, wqkvt, nullptr, qf, SEQ, 3 * DMODEL, DMODEL, 2, kf, vb);
    copelogits_k<<<SEQ, 256, 0, stream>>>(qf, pos_emb, li);
    tv_k<<<dim3(SEQ / 64, NH), 256, 0, stream>>>((const ushort_t*)vb, (ushort_t*)vt);

    // ---- phase 2: attention chunks ----
    for (int ch = 0; ch < NCH; ch++) {
        int cb = ch * CHUNK;
        scoresm_k<<<dim3(SEQ / 128, CHUNK / 128, NH), 256, 0, stream>>>(qf, kf, sc, cb);
        cope_k<<<CHUNK, 1024, 0, stream>>>(sc, li, mlp_w1, mlp_b1, mlp_w2, mlp_b2, cb);
        pvm_k<<<dim3(CHUNK / 32, NH), 256, 0, stream>>>(sc, (const ushort_t*)vt, aob, cb);
    }

    // ---- phase B: out @ wo + x (64-tile, 512 blocks) ----
    transconv_k<<<dim3(DMODEL / 64, DMODEL / 64), 256, 0, stream>>>(wo, wot, DMODEL, DMODEL);
    gemm64_k<<<dim3(DMODEL / 64, SEQ / 64), 256, 0, stream>>>(
        aob, wot, x, x1, SEQ, DMODEL, DMODEL, 0, nullptr, nullptr);

    // ---- phase C: FFN ----
    rmsnormf_k<<<SEQ, 256, 0, stream>>>(x1, ffn_norm_w, nxb2);
    transconv2_k<<<dim3(FFDIM / 64, DMODEL / 64), 256, 0, stream>>>(ffn_w1, ffn_w3, w13t, DMODEL, FFDIM);
    transconv_k<<<dim3(DMODEL / 64, FFDIM / 64), 256, 0, stream>>>(ffn_w2, w2t, FFDIM, DMODEL);
    gemm128_k<<<dim3(2 * FFDIM / 128, SEQ / 128), 256, 0, stream>>>(
        nxb2, w13t, nullptr, g1b, SEQ, 2 * FFDIM, DMODEL, 4);
    gemm64_k<<<dim3(DMODEL / 64, SEQ / 64), 256, 0, stream>>>(
        g1b, w2t, x1, out, SEQ, DMODEL, FFDIM, 0, nullptr, nullptr);
}

// Round 20
// 415.777 us; speedup vs baseline: 1.0614x; 1.0226x over previous
//
#include <hip/hip_runtime.h>
#include <hip/hip_bf16.h>
#include <hip/hip_fp16.h>
#include <math.h>

#define SEQ 2048
#define DMODEL 1024
#define NH 16
#define DHEAD 64
#define FFDIM 4096
#define NPOSE 128
#define MLPWID 32
#define EPSV 1e-5f
#define CHUNK 1024
#define NCH (SEQ / CHUNK)

typedef unsigned short ushort_t;
typedef unsigned int uint_t;
typedef _Float16 f16;
typedef __attribute__((ext_vector_type(8))) _Float16 f16x8;
typedef __attribute__((ext_vector_type(4))) float f32x4;

union HF8 { f16x8 v; f16 h[8]; ushort_t s[8]; uint2 u2[2]; uint4 u4; };
union U1H2 { uint_t u; f16 h[2]; };
union U2H4 { uint2 u; f16 h[4]; };

__device__ __forceinline__ float sigm(float x) {
    return __builtin_amdgcn_rcpf(1.0f + __expf(-x));
}
__device__ __forceinline__ void gl_lds16(const void* g, void* l) {
    __builtin_amdgcn_global_load_lds((const __attribute__((address_space(1))) uint_t*)g,
                                     (__attribute__((address_space(3))) uint_t*)l, 16, 0, 0);
}

// ---------------- RMSNorm, f16 out ----------------
__global__ __launch_bounds__(256) void rmsnormf_k(const float* __restrict__ x,
                                                  const float* __restrict__ w,
                                                  f16* __restrict__ o) {
    int row = blockIdx.x;
    int tid = threadIdx.x;
    const float4* xr = (const float4*)(x + (size_t)row * DMODEL);
    float4 v = xr[tid];
    float ss = v.x * v.x + v.y * v.y + v.z * v.z + v.w * v.w;
#pragma unroll
    for (int d = 1; d < 64; d <<= 1) ss += __shfl_xor(ss, d, 64);
    __shared__ float red[4];
    int lane = tid & 63, wv = tid >> 6;
    if (lane == 0) red[wv] = ss;
    __syncthreads();
    float tot = red[0] + red[1] + red[2] + red[3];
    float r = rsqrtf(tot / (float)DMODEL + EPSV);
    const float4* wr = (const float4*)w;
    float4 wv4 = wr[tid];
    U2H4 ob;
    ob.h[0] = (f16)(v.x * r * wv4.x);
    ob.h[1] = (f16)(v.y * r * wv4.y);
    ob.h[2] = (f16)(v.z * r * wv4.z);
    ob.h[3] = (f16)(v.w * r * wv4.w);
    ((uint2*)(o + (size_t)row * DMODEL))[tid] = ob.u;
}

// ---------------- V transpose ----------------
__global__ __launch_bounds__(256) void tv_k(const ushort_t* __restrict__ vb,
                                            ushort_t* __restrict__ vt) {
    int h = blockIdx.y, t0 = blockIdx.x * 64;
    __shared__ ushort_t T[64][76];
    int tid = threadIdx.x;
#pragma unroll
    for (int it = 0; it < 2; it++) {
        int a = tid + it * 256;
        int t = a >> 3, c8 = (a & 7) * 8;
        HF8 v;
        v.u4 = *(const uint4*)(vb + (size_t)(t0 + t) * DMODEL + h * 64 + c8);
#pragma unroll
        for (int j = 0; j < 8; j++) T[c8 + j][t] = v.s[j];
    }
    __syncthreads();
#pragma unroll
    for (int it = 0; it < 2; it++) {
        int a = tid + it * 256;
        int d = a >> 3, c8 = (a & 7) * 8;
        HF8 o;
#pragma unroll
        for (int j = 0; j < 8; j++) o.s[j] = T[d][c8 + j];
        *(uint4*)(vt + ((size_t)h * 64 + d) * SEQ + t0 + c8) = o.u4;
    }
}

// ---------------- weight transpose+convert: f32[K][N] -> f16[N][K] ----------------
__global__ __launch_bounds__(256) void transconv_k(const float* __restrict__ in,
                                                   f16* __restrict__ out,
                                                   int K, int N) {
    __shared__ f16 T[64][72];
    int k0 = blockIdx.y * 64, n0 = blockIdx.x * 64;
    int tid = threadIdx.x;
    int r = tid >> 4, c4 = (tid & 15) * 4;
#pragma unroll
    for (int i = 0; i < 4; i++) {
        float4 v = *(const float4*)(in + (size_t)(k0 + r + i * 16) * N + n0 + c4);
        T[c4 + 0][r + i * 16] = (f16)v.x;
        T[c4 + 1][r + i * 16] = (f16)v.y;
        T[c4 + 2][r + i * 16] = (f16)v.z;
        T[c4 + 3][r + i * 16] = (f16)v.w;
    }
    __syncthreads();
    int n = tid >> 2, kk = (tid & 3) * 16;
    uint4* dst = (uint4*)(out + (size_t)(n0 + n) * K + k0 + kk);
    dst[0] = *(const uint4*)&T[n][kk];
    dst[1] = *(const uint4*)&T[n][kk + 8];
}

// ---------------- 3-way weight transpose (QKV) via blockIdx.z ----------------
__global__ __launch_bounds__(256) void transconv3_k(const float* __restrict__ w0,
                                                    const float* __restrict__ w1p,
                                                    const float* __restrict__ w2p,
                                                    f16* __restrict__ out) {
    const int K = DMODEL, N = DMODEL;
    const float* in = (blockIdx.z == 0) ? w0 : (blockIdx.z == 1) ? w1p : w2p;
    f16* o = out + (size_t)blockIdx.z * DMODEL * DMODEL;
    __shared__ f16 T[64][72];
    int k0 = blockIdx.y * 64, n0 = blockIdx.x * 64;
    int tid = threadIdx.x;
    int r = tid >> 4, c4 = (tid & 15) * 4;
#pragma unroll
    for (int i = 0; i < 4; i++) {
        float4 v = *(const float4*)(in + (size_t)(k0 + r + i * 16) * N + n0 + c4);
        T[c4 + 0][r + i * 16] = (f16)v.x;
        T[c4 + 1][r + i * 16] = (f16)v.y;
        T[c4 + 2][r + i * 16] = (f16)v.z;
        T[c4 + 3][r + i * 16] = (f16)v.w;
    }
    __syncthreads();
    int n = tid >> 2, kk = (tid & 3) * 16;
    uint4* dst = (uint4*)(o + (size_t)(n0 + n) * K + k0 + kk);
    dst[0] = *(const uint4*)&T[n][kk];
    dst[1] = *(const uint4*)&T[n][kk + 8];
}

// ---------------- w1/w3 transpose+convert, row-interleaved ----------------
__global__ __launch_bounds__(256) void transconv2_k(const float* __restrict__ w1,
                                                    const float* __restrict__ w3,
                                                    f16* __restrict__ out,
                                                    int K, int N) {
    __shared__ f16 T[64][72];
    int k0 = blockIdx.y * 64, n0 = blockIdx.x * 64;
    int tid = threadIdx.x;
    int r = tid >> 4, c4 = (tid & 15) * 4;
    int n = tid >> 2, kk = (tid & 3) * 16;
#pragma unroll
    for (int half = 0; half < 2; half++) {
        const float* in = half ? w3 : w1;
#pragma unroll
        for (int i = 0; i < 4; i++) {
            float4 v = *(const float4*)(in + (size_t)(k0 + r + i * 16) * N + n0 + c4);
            T[c4 + 0][r + i * 16] = (f16)v.x;
            T[c4 + 1][r + i * 16] = (f16)v.y;
            T[c4 + 2][r + i * 16] = (f16)v.z;
            T[c4 + 3][r + i * 16] = (f16)v.w;
        }
        __syncthreads();
        int gc = n0 + n;
        int rp = (gc >> 4) * 32 + (gc & 15) + half * 16;
        uint4* dst = (uint4*)(out + (size_t)rp * K + k0 + kk);
        dst[0] = *(const uint4*)&T[n][kk];
        dst[1] = *(const uint4*)&T[n][kk + 8];
        __syncthreads();
    }
}

// ---------------- f16 MFMA GEMM 128x128 (TN), BK=64, XOR-swizzled LDS, XCD-swizzled ----------------
// mode 0: f32 out (+add). mode 1: f16 out. mode 4: w1w3-interleaved silu-mul.
__global__ __launch_bounds__(256) void gemm128_k(const f16* __restrict__ A,
                                                 const f16* __restrict__ Bt,
                                                 const float* __restrict__ add,
                                                 void* __restrict__ Cout,
                                                 int M, int N, int K, int mode) {
    __shared__ f16 Al[128 * 64];
    __shared__ f16 Bl[128 * 64];
    int tid = threadIdx.x;
    int lane = tid & 63, wave = tid >> 6;
    int gx = gridDim.x, gy = gridDim.y;
    int nwg = gx * gy;
    int bx = blockIdx.x, by = blockIdx.y;
    if ((nwg & 7) == 0) {
        int flat = by * gx + bx;
        int cpx = nwg >> 3;
        int l = (flat & 7) * cpx + (flat >> 3);
        bx = l / gy;
        by = l % gy;
    }
    int brow = by * 128, bcol = bx * 128;
    int wr = (wave >> 1) * 64, wc = (wave & 1) * 64;
    f32x4 acc[4][4];
#pragma unroll
    for (int m = 0; m < 4; m++)
#pragma unroll
        for (int n = 0; n < 4; n++) acc[m][n] = (f32x4){0.f, 0.f, 0.f, 0.f};

    int srow = tid >> 3;
    int scol = (((tid & 7) ^ (srow & 7)) * 8);
    const f16* Ag = A + (size_t)(brow + srow) * K + scol;
    const f16* Bg = Bt + (size_t)(bcol + srow) * K + scol;
    f16* Ald = &Al[wave * 512];
    f16* Bld = &Bl[wave * 512];
    size_t rstep32 = (size_t)32 * K;

    for (int k0 = 0; k0 < K; k0 += 64) {
#pragma unroll
        for (int i = 0; i < 4; i++) {
            gl_lds16(Ag + i * rstep32 + k0, Ald + i * 2048);
            gl_lds16(Bg + i * rstep32 + k0, Bld + i * 2048);
        }
        __syncthreads();
#pragma unroll
        for (int ks = 0; ks < 2; ks++) {
            f16x8 af[4], bfr[4];
            int gbase = ks * 4 + (lane >> 4);
#pragma unroll
            for (int m = 0; m < 4; m++) {
                int r = wr + m * 16 + (lane & 15);
                af[m] = *(const f16x8*)&Al[r * 64 + ((gbase ^ (r & 7)) * 8)];
            }
#pragma unroll
            for (int n = 0; n < 4; n++) {
                int r = wc + n * 16 + (lane & 15);
                bfr[n] = *(const f16x8*)&Bl[r * 64 + ((gbase ^ (r & 7)) * 8)];
            }
#pragma unroll
            for (int m = 0; m < 4; m++)
#pragma unroll
                for (int n = 0; n < 4; n++)
                    acc[m][n] = __builtin_amdgcn_mfma_f32_16x16x32_f16(af[m], bfr[n], acc[m][n], 0, 0, 0);
        }
        __syncthreads();
    }
    int crow0 = brow + wr + (lane >> 4) * 4;
    int ccol = bcol + wc + (lane & 15);
#pragma unroll
    for (int m = 0; m < 4; m++)
#pragma unroll
        for (int j = 0; j < 4; j++) {
            int row = crow0 + m * 16 + j;
            if (mode == 4) {
#pragma unroll
                for (int n = 0; n < 4; n += 2) {
                    int c = ccol + n * 16;
                    int colOut = (c >> 5) * 16 + (c & 15);
                    float v1 = acc[m][n][j];
                    float v3 = acc[m][n + 1][j];
                    ((f16*)Cout)[(size_t)row * (N / 2) + colOut] =
                        (f16)(v1 * sigm(v1) * v3);
                }
            } else {
#pragma unroll
                for (int n = 0; n < 4; n++) {
                    int col = ccol + n * 16;
                    float v = acc[m][n][j];
                    if (mode == 0) {
                        if (add) v += add[(size_t)row * N + col];
                        ((float*)Cout)[(size_t)row * N + col] = v;
                    } else {
                        ((f16*)Cout)[(size_t)row * N + col] = (f16)v;
                    }
                }
            }
        }
}

// ---------------- f16 MFMA GEMM 64x64 (TN), BK=64, XOR-swizzled LDS, XCD-swizzled ----------------
// mode 0: f32 out (+add). mode 1: f16. mode 2: qkv split (Cout=q, p2=k, p3=v).
__global__ __launch_bounds__(256) void gemm64_k(const f16* __restrict__ A,
                                                const f16* __restrict__ Bt,
                                                const float* __restrict__ add,
                                                void* __restrict__ Cout,
                                                int M, int N, int K, int mode,
                                                f16* __restrict__ p2,
                                                f16* __restrict__ p3) {
    __shared__ f16 Al[64 * 64];
    __shared__ f16 Bl[64 * 64];
    int tid = threadIdx.x;
    int lane = tid & 63, wave = tid >> 6;
    int gx = gridDim.x, gy = gridDim.y;
    int nwg = gx * gy;
    int bx = blockIdx.x, by = blockIdx.y;
    if ((nwg & 7) == 0) {
        int flat = by * gx + bx;
        int cpx = nwg >> 3;
        int l = (flat & 7) * cpx + (flat >> 3);
        bx = l / gy;
        by = l % gy;
    }
    int brow = by * 64, bcol = bx * 64;
    int wr = (wave >> 1) * 32, wc = (wave & 1) * 32;
    f32x4 acc[2][2];
#pragma unroll
    for (int m = 0; m < 2; m++)
#pragma unroll
        for (int n = 0; n < 2; n++) acc[m][n] = (f32x4){0.f, 0.f, 0.f, 0.f};

    int srow = tid >> 3;                     // 0..31
    int scol = (((tid & 7) ^ (srow & 7)) * 8);
    const f16* Ag = A + (size_t)(brow + srow) * K + scol;
    const f16* Bg = Bt + (size_t)(bcol + srow) * K + scol;
    f16* Ald = &Al[wave * 512];
    f16* Bld = &Bl[wave * 512];
    size_t rstep32 = (size_t)32 * K;

    for (int k0 = 0; k0 < K; k0 += 64) {
        gl_lds16(Ag + k0, Ald);
        gl_lds16(Ag + rstep32 + k0, Ald + 2048);
        gl_lds16(Bg + k0, Bld);
        gl_lds16(Bg + rstep32 + k0, Bld + 2048);
        __syncthreads();
#pragma unroll
        for (int ks = 0; ks < 2; ks++) {
            f16x8 af[2], bfr[2];
            int gbase = ks * 4 + (lane >> 4);
#pragma unroll
            for (int m = 0; m < 2; m++) {
                int r = wr + m * 16 + (lane & 15);
                af[m] = *(const f16x8*)&Al[r * 64 + ((gbase ^ (r & 7)) * 8)];
            }
#pragma unroll
            for (int n = 0; n < 2; n++) {
                int r = wc + n * 16 + (lane & 15);
                bfr[n] = *(const f16x8*)&Bl[r * 64 + ((gbase ^ (r & 7)) * 8)];
            }
#pragma unroll
            for (int m = 0; m < 2; m++)
#pragma unroll
                for (int n = 0; n < 2; n++)
                    acc[m][n] = __builtin_amdgcn_mfma_f32_16x16x32_f16(af[m], bfr[n], acc[m][n], 0, 0, 0);
        }
        __syncthreads();
    }
    int crow0 = brow + wr + (lane >> 4) * 4;
    int ccol = bcol + wc + (lane & 15);
#pragma unroll
    for (int m = 0; m < 2; m++)
#pragma unroll
        for (int j = 0; j < 4; j++) {
            int row = crow0 + m * 16 + j;
#pragma unroll
            for (int n = 0; n < 2; n++) {
                int col = ccol + n * 16;
                float v = acc[m][n][j];
                if (mode == 0) {
                    if (add) v += add[(size_t)row * N + col];
                    ((float*)Cout)[(size_t)row * N + col] = v;
                } else if (mode == 1) {
                    ((f16*)Cout)[(size_t)row * N + col] = (f16)v;
                } else {
                    size_t o = (size_t)row * DMODEL;
                    if (col < DMODEL) ((f16*)Cout)[o + col] = (f16)v;
                    else if (col < 2 * DMODEL) p2[o + col - DMODEL] = (f16)v;
                    else p3[o + col - 2 * DMODEL] = (f16)v;
                }
            }
        }
}

// ---------------- MFMA scores, 128x128 tile ----------------
__global__ __launch_bounds__(256) void scoresm_k(const f16* __restrict__ qf,
                                                 const f16* __restrict__ kf,
                                                 f16* __restrict__ sc, int cb) {
    int h = blockIdx.z;
    int il0 = blockIdx.y * 128;
    int j0 = blockIdx.x * 128;
    __shared__ f16 Qf[128][72];
    __shared__ f16 Kf[128][72];
    int tid = threadIdx.x;
#pragma unroll
    for (int i = 0; i < 4; i++) {
        int row = i * 32 + (tid >> 3);
        int c8 = (tid & 7) * 8;
        *(uint4*)&Qf[row][c8] =
            *(const uint4*)(qf + (size_t)(cb + il0 + row) * DMODEL + h * 64 + c8);
        *(uint4*)&Kf[row][c8] =
            *(const uint4*)(kf + (size_t)(j0 + row) * DMODEL + h * 64 + c8);
    }
    __syncthreads();
    int lane = tid & 63, wave = tid >> 6;
    int wr = (wave >> 1) * 64, wc = (wave & 1) * 64;
    f32x4 acc[4][4];
#pragma unroll
    for (int m = 0; m < 4; m++)
#pragma unroll
        for (int n = 0; n < 4; n++) acc[m][n] = (f32x4){0.f, 0.f, 0.f, 0.f};
#pragma unroll
    for (int ks = 0; ks < 2; ks++) {
        int kof = ks * 32 + (lane >> 4) * 8;
        f16x8 aQ[4], bK[4];
#pragma unroll
        for (int m = 0; m < 4; m++)
            aQ[m] = *(const f16x8*)&Qf[wr + m * 16 + (lane & 15)][kof];
#pragma unroll
        for (int n = 0; n < 4; n++)
            bK[n] = *(const f16x8*)&Kf[wc + n * 16 + (lane & 15)][kof];
#pragma unroll
        for (int m = 0; m < 4; m++)
#pragma unroll
            for (int n = 0; n < 4; n++)
                acc[m][n] = __builtin_amdgcn_mfma_f32_16x16x32_f16(aQ[m], bK[n], acc[m][n], 0, 0, 0);
    }
#pragma unroll
    for (int m = 0; m < 4; m++)
#pragma unroll
        for (int j = 0; j < 4; j++) {
            int il = il0 + wr + m * 16 + (lane >> 4) * 4 + j;
#pragma unroll
            for (int n = 0; n < 4; n++) {
                int jj = j0 + wc + n * 16 + (lane & 15);
                sc[((size_t)h * CHUNK + il) * SEQ + jj] = (f16)(acc[m][n][j] * 0.125f);
            }
        }
}

// ---------------- logits_int -> f16 ----------------
__global__ __launch_bounds__(256) void copelogits_k(const f16* __restrict__ qf,
                                                    const float* __restrict__ pe,
                                                    f16* __restrict__ li) {
    int s1 = blockIdx.x;
    int tid = threadIdx.x;
    __shared__ float PE[DHEAD * NPOSE];
    __shared__ float QR[DMODEL];
    for (int i = tid; i < DHEAD * NPOSE; i += 256) PE[i] = pe[i];
    for (int i = tid; i < DMODEL; i += 256) QR[i] = (float)qf[(size_t)s1 * DMODEL + i];
    __syncthreads();
#pragma unroll
    for (int j = 0; j < 8; j++) {
        int o = j * 256 + tid;
        int h = o >> 7, n = o & 127;
        const float* qhp = &QR[h * DHEAD];
        float acc = 0.0f;
#pragma unroll 8
        for (int d = 0; d < DHEAD; d++) acc += qhp[d] * PE[d * NPOSE + n];
        li[(size_t)s1 * (NH * NPOSE) + o] = (f16)acc;
    }
}

// ---------------- fused CoPE: ILP scan + bias + f16 MFMA MLP + softmax -> P ----------------
#define CSTR 2052
__global__ __launch_bounds__(1024, 1) void cope_k(f16* __restrict__ sc,
                                                  const f16* __restrict__ li,
                                                  const float* __restrict__ w1,
                                                  const float* __restrict__ b1,
                                                  const float* __restrict__ w2,
                                                  const float* __restrict__ b2,
                                                  int cb) {
    __shared__ f16 C[32 * CSTR];
    __shared__ uint_t Lif2[NH * 130];
    __shared__ f16 HMB[16][16 * 36];
    int r = blockIdx.x;
    int tid = threadIdx.x;
    int lane = tid & 63, wv = tid >> 6;

    const f16* srow = sc + ((size_t)wv * CHUNK + r) * SEQ;
    HF8 rv[4];
#pragma unroll
    for (int c = 0; c < 4; c++) rv[c].u4 = *(const uint4*)&srow[c * 512 + lane * 8];

    {
        const f16* lh = li + (size_t)(cb + r) * (NH * NPOSE) + wv * NPOSE;
#pragma unroll
        for (int e = 0; e < 2; e++) {
            int n = lane + e * 64;
            U1H2 pk;
            pk.h[0] = lh[n];
            pk.h[1] = lh[(n < NPOSE - 1) ? n + 1 : NPOSE - 1];
            Lif2[wv * 130 + n] = pk.u;
        }
    }

    {
        f16* crow = &C[wv * CSTR];
        f16* brow = &C[(16 + wv) * CSTR];
        const uint_t* lrow = &Lif2[wv * 130];
        float g[4][8];
        float S[4];
#pragma unroll
        for (int c = 0; c < 4; c++) {
            HF8 sv = rv[c];
            float s = 0.0f;
#pragma unroll
            for (int e = 0; e < 8; e++) {
                g[c][e] = sigm((float)sv.h[e]);
                s += g[c][e];
            }
            S[c] = s;
        }
#pragma unroll
        for (int dd = 1; dd < 64; dd <<= 1) {
#pragma unroll
            for (int c = 0; c < 4; c++) {
                float o = __shfl_down(S[c], dd, 64);
                S[c] = (lane + dd < 64) ? S[c] + o : S[c];
            }
        }
        float tot[4];
#pragma unroll
        for (int c = 0; c < 4; c++) tot[c] = __shfl(S[c], 0, 64);
        float carry[4];
        carry[3] = 0.0f;
        carry[2] = tot[3];
        carry[1] = tot[3] + tot[2];
        carry[0] = carry[1] + tot[1];
#pragma unroll
        for (int c = 0; c < 4; c++) {
            float p = S[c] + carry[c];
            HF8 bo;
#pragma unroll
            for (int e = 0; e < 8; e++) {
                float pos = fminf(p, 127.0f);
                int fl = (int)pos;
                float fr = pos - (float)fl;
                U1H2 lv;
                lv.u = lrow[fl];
                float lf = (float)lv.h[0];
                bo.h[e] = (f16)(lf + ((float)lv.h[1] - lf) * fr);
                p -= g[c][e];
            }
            int t = c * 512 + lane * 8;
            *(uint4*)&crow[t] = rv[c].u4;
            *(uint4*)&brow[t] = bo.u4;
        }
    }
    __syncthreads();

    int fkg = lane >> 4;
    int fc = lane & 15;
    HF8 w1f[2], w2f;
    float b1v[2], b2v;
#pragma unroll
    for (int half = 0; half < 2; half++) {
#pragma unroll
        for (int j = 0; j < 8; j++)
            w1f[half].h[j] = (f16)w1[(fkg * 8 + j) * MLPWID + half * 16 + fc];
        b1v[half] = b1[half * 16 + fc];
    }
#pragma unroll
    for (int j = 0; j < 8; j++) w2f.h[j] = (f16)w2[(fkg * 8 + j) * NH + fc];
    b2v = b2[fc];

    f16* hmb = HMB[wv];
#pragma unroll 2
    for (int tt = wv; tt < SEQ / 16; tt += 16) {
        int t0 = tt * 16;
        HF8 af;
#pragma unroll
        for (int j = 0; j < 8; j++) af.h[j] = C[(fkg * 8 + j) * CSTR + t0 + fc];
        f32x4 acc0 = (f32x4){b1v[0], b1v[0], b1v[0], b1v[0]};
        f32x4 acc1 = (f32x4){b1v[1], b1v[1], b1v[1], b1v[1]};
        acc0 = __builtin_amdgcn_mfma_f32_16x16x32_f16(af.v, w1f[0].v, acc0, 0, 0, 0);
        acc1 = __builtin_amdgcn_mfma_f32_16x16x32_f16(af.v, w1f[1].v, acc1, 0, 0, 0);
#pragma unroll
        for (int j2 = 0; j2 < 4; j2++) {
            int p = fkg * 4 + j2;
            float h0 = acc0[j2]; h0 = h0 * sigm(h0);
            float h1 = acc1[j2]; h1 = h1 * sigm(h1);
            hmb[p * 36 + fc] = (f16)h0;
            hmb[p * 36 + 16 + fc] = (f16)h1;
        }
        HF8 hf;
        hf.u2[0] = *(const uint2*)&hmb[fc * 36 + fkg * 8];
        hf.u2[1] = *(const uint2*)&hmb[fc * 36 + fkg * 8 + 4];
        f32x4 acc2 = (f32x4){b2v, b2v, b2v, b2v};
        acc2 = __builtin_amdgcn_mfma_f32_16x16x32_f16(hf.v, w2f.v, acc2, 0, 0, 0);
#pragma unroll
        for (int j2 = 0; j2 < 4; j2 += 2) {
            uint_t* pp = (uint_t*)&C[fc * CSTR + t0 + fkg * 4 + j2];
            U1H2 old, neu;
            old.u = *pp;
            neu.h[0] = (f16)((float)old.h[0] + acc2[j2]);
            neu.h[1] = (f16)((float)old.h[1] + acc2[j2 + 1]);
            *pp = neu.u;
        }
    }
    __syncthreads();

    {
        const f16* row = &C[wv * CSTR];
        float vals[32];
        float m = -1e30f;
#pragma unroll
        for (int c = 0; c < 4; c++) {
            HF8 sv;
            sv.u4 = *(const uint4*)&row[c * 512 + lane * 8];
#pragma unroll
            for (int e = 0; e < 8; e++) {
                vals[c * 8 + e] = (float)sv.h[e];
                m = fmaxf(m, vals[c * 8 + e]);
            }
        }
#pragma unroll
        for (int d = 1; d < 64; d <<= 1) m = fmaxf(m, __shfl_xor(m, d, 64));
        float s = 0.0f;
#pragma unroll
        for (int c = 0; c < 32; c++) {
            vals[c] = __expf(vals[c] - m);
            s += vals[c];
        }
#pragma unroll
        for (int d = 1; d < 64; d <<= 1) s += __shfl_xor(s, d, 64);
        float ri = __builtin_amdgcn_rcpf(s);
        f16* dst = sc + ((size_t)wv * CHUNK + r) * SEQ;
#pragma unroll
        for (int c = 0; c < 4; c++) {
            HF8 po;
#pragma unroll
            for (int e = 0; e < 8; e++) po.h[e] = (f16)(vals[c * 8 + e] * ri);
            *(uint4*)&dst[c * 512 + lane * 8] = po.u4;
        }
    }
}

// ---------------- f16 MFMA PV ----------------
__global__ __launch_bounds__(256) void pvm_k(const f16* __restrict__ scP,
                                             const ushort_t* __restrict__ vt,
                                             f16* __restrict__ aob, int cb) {
    int h = blockIdx.y;
    int s0 = blockIdx.x * 32;
    __shared__ f16 P[32][72];
    __shared__ f16 Vt[64][72];
    int tid = threadIdx.x;
    int lane = tid & 63, wave = tid >> 6;
    int wr = (wave >> 1) * 16, wc = (wave & 1) * 32;
    f32x4 acc[2];
    acc[0] = (f32x4){0.f, 0.f, 0.f, 0.f};
    acc[1] = (f32x4){0.f, 0.f, 0.f, 0.f};
    int pr = tid >> 3, pc = (tid & 7) * 8;
    int vr = tid >> 2, vc = (tid & 3) * 16;
    for (int t0 = 0; t0 < SEQ; t0 += 64) {
        {
            *(uint4*)&P[pr][pc] =
                *(const uint4*)(scP + ((size_t)h * CHUNK + s0 + pr) * SEQ + t0 + pc);
            const ushort_t* vp = vt + ((size_t)h * 64 + vr) * SEQ + t0 + vc;
            *(uint4*)&Vt[vr][vc] = *(const uint4*)vp;
            *(uint4*)&Vt[vr][vc + 8] = *(const uint4*)(vp + 8);
        }
        __syncthreads();
#pragma unroll
        for (int ks = 0; ks < 2; ks++) {
            int kof = ks * 32 + (lane >> 4) * 8;
            f16x8 pa = *(const f16x8*)&P[wr + (lane & 15)][kof];
#pragma unroll
            for (int n = 0; n < 2; n++) {
                f16x8 vb = *(const f16x8*)&Vt[wc + n * 16 + (lane & 15)][kof];
                acc[n] = __builtin_amdgcn_mfma_f32_16x16x32_f16(pa, vb, acc[n], 0, 0, 0);
            }
        }
        __syncthreads();
    }
#pragma unroll
    for (int j = 0; j < 4; j++) {
        int s = cb + s0 + wr + (lane >> 4) * 4 + j;
#pragma unroll
        for (int n = 0; n < 2; n++) {
            int d = h * 64 + wc + n * 16 + (lane & 15);
            aob[(size_t)s * DMODEL + d] = (f16)acc[n][j];
        }
    }
}

extern "C" void kernel_launch(void* const* d_in, const int* in_sizes, int n_in,
                              void* d_out, int out_size, void* d_ws, size_t ws_size,
                              hipStream_t stream) {
    const float* x = (const float*)d_in[0];
    const float* wq = (const float*)d_in[1];
    const float* wk = (const float*)d_in[2];
    const float* wv = (const float*)d_in[3];
    const float* wo = (const float*)d_in[4];
    const float* pos_emb = (const float*)d_in[5];
    const float* mlp_w1 = (const float*)d_in[6];
    const float* mlp_b1 = (const float*)d_in[7];
    const float* mlp_w2 = (const float*)d_in[8];
    const float* mlp_b2 = (const float*)d_in[9];
    const float* ffn_w1 = (const float*)d_in[10];
    const float* ffn_w2 = (const float*)d_in[11];
    const float* ffn_w3 = (const float*)d_in[12];
    const float* attn_norm_w = (const float*)d_in[13];
    const float* ffn_norm_w = (const float*)d_in[14];
    float* out = (float*)d_out;

    char* ws = (char*)d_ws;
    const size_t MB = 1024 * 1024;
    f16* nxb = (f16*)(ws + 0);               // 0-4
    f16* qf = (f16*)(ws + 4 * MB);           // 4-8   (phase C: nxb2)
    f16* kf = (f16*)(ws + 8 * MB);           // 8-12  (phase C: g1b 8-24)
    f16* vb = (f16*)(ws + 12 * MB);          // 12-16
    f16* vt = (f16*)(ws + 16 * MB);          // 16-20
    f16* li = (f16*)(ws + 20 * MB);          // 20-28
    f16* aob = (f16*)(ws + 28 * MB);         // 28-32
    float* x1 = (float*)(ws + 32 * MB);      // 32-40
    f16* wqkvt = (f16*)(ws + 40 * MB);       // 40-46 (phase 1)
    f16* sc = (f16*)(ws + 40 * MB);          // 40-104 (phase 2, CHUNK=1024)
    f16* wot = (f16*)(ws + 40 * MB);         // 40-42 (phase B)
    f16* w13t = (f16*)(ws + 40 * MB);        // 40-56 (phase C, interleaved)
    f16* w2t = (f16*)(ws + 56 * MB);         // 56-64
    f16* nxb2 = (f16*)(ws + 4 * MB);
    f16* g1b = (f16*)(ws + 8 * MB);          // 8-24

    // ---- phase 1: norm + fused QKV (64-tile, 1536 blocks) ----
    transconv3_k<<<dim3(DMODEL / 64, DMODEL / 64, 3), 256, 0, stream>>>(wq, wk, wv, wqkvt);
    rmsnormf_k<<<SEQ, 256, 0, stream>>>(x, attn_norm_w, nxb);
    gemm64_k<<<dim3(3 * DMODEL / 64, SEQ / 64), 256, 0, stream>>>(
        nxb, wqkvt, nullptr, qf, SEQ, 3 * DMODEL, DMODEL, 2, kf, vb);
    copelogits_k<<<SEQ, 256, 0, stream>>>(qf, pos_emb, li);
    tv_k<<<dim3(SEQ / 64, NH), 256, 0, stream>>>((const ushort_t*)vb, (ushort_t*)vt);

    // ---- phase 2: attention chunks ----
    for (int ch = 0; ch < NCH; ch++) {
        int cb = ch * CHUNK;
        scoresm_k<<<dim3(SEQ / 128, CHUNK / 128, NH), 256, 0, stream>>>(qf, kf, sc, cb);
        cope_k<<<CHUNK, 1024, 0, stream>>>(sc, li, mlp_w1, mlp_b1, mlp_w2, mlp_b2, cb);
        pvm_k<<<dim3(CHUNK / 32, NH), 256, 0, stream>>>(sc, (const ushort_t*)vt, aob, cb);
    }

    // ---- phase B: out @ wo + x (64-tile, 512 blocks) ----
    transconv_k<<<dim3(DMODEL / 64, DMODEL / 64), 256, 0, stream>>>(wo, wot, DMODEL, DMODEL);
    gemm64_k<<<dim3(DMODEL / 64, SEQ / 64), 256, 0, stream>>>(
        aob, wot, x, x1, SEQ, DMODEL, DMODEL, 0, nullptr, nullptr);

    // ---- phase C: FFN ----
    rmsnormf_k<<<SEQ, 256, 0, stream>>>(x1, ffn_norm_w, nxb2);
    transconv2_k<<<dim3(FFDIM / 64, DMODEL / 64), 256, 0, stream>>>(ffn_w1, ffn_w3, w13t, DMODEL, FFDIM);
    transconv_k<<<dim3(DMODEL / 64, FFDIM / 64), 256, 0, stream>>>(ffn_w2, w2t, FFDIM, DMODEL);
    gemm128_k<<<dim3(2 * FFDIM / 128, SEQ / 128), 256, 0, stream>>>(
        nxb2, w13t, nullptr, g1b, SEQ, 2 * FFDIM, DMODEL, 4);
    gemm64_k<<<dim3(DMODEL / 64, SEQ / 64), 256, 0, stream>>>(
        g1b, w2t, x1, out, SEQ, DMODEL, FFDIM, 0, nullptr, nullptr);
}

// Round 21
// 410.284 us; speedup vs baseline: 1.0756x; 1.0134x over previous
//
#include <hip/hip_runtime.h>
#include <hip/hip_bf16.h>
#include <hip/hip_fp16.h>
#include <math.h>

#define SEQ 2048
#define DMODEL 1024
#define NH 16
#define DHEAD 64
#define FFDIM 4096
#define NPOSE 128
#define MLPWID 32
#define EPSV 1e-5f
#define CHUNK 1024
#define NCH (SEQ / CHUNK)

typedef unsigned short ushort_t;
typedef unsigned int uint_t;
typedef _Float16 f16;
typedef __attribute__((ext_vector_type(8))) _Float16 f16x8;
typedef __attribute__((ext_vector_type(4))) float f32x4;

union HF8 { f16x8 v; f16 h[8]; ushort_t s[8]; uint2 u2[2]; uint4 u4; };
union U1H2 { uint_t u; f16 h[2]; };
union U2H4 { uint2 u; f16 h[4]; };

__device__ __forceinline__ float sigm(float x) {
    return __builtin_amdgcn_rcpf(1.0f + __expf(-x));
}
__device__ __forceinline__ void gl_lds16(const void* g, void* l) {
    __builtin_amdgcn_global_load_lds((const __attribute__((address_space(1))) uint_t*)g,
                                     (__attribute__((address_space(3))) uint_t*)l, 16, 0, 0);
}

// ---------------- RMSNorm, f16 out ----------------
__global__ __launch_bounds__(256) void rmsnormf_k(const float* __restrict__ x,
                                                  const float* __restrict__ w,
                                                  f16* __restrict__ o) {
    int row = blockIdx.x;
    int tid = threadIdx.x;
    const float4* xr = (const float4*)(x + (size_t)row * DMODEL);
    float4 v = xr[tid];
    float ss = v.x * v.x + v.y * v.y + v.z * v.z + v.w * v.w;
#pragma unroll
    for (int d = 1; d < 64; d <<= 1) ss += __shfl_xor(ss, d, 64);
    __shared__ float red[4];
    int lane = tid & 63, wv = tid >> 6;
    if (lane == 0) red[wv] = ss;
    __syncthreads();
    float tot = red[0] + red[1] + red[2] + red[3];
    float r = rsqrtf(tot / (float)DMODEL + EPSV);
    const float4* wr = (const float4*)w;
    float4 wv4 = wr[tid];
    U2H4 ob;
    ob.h[0] = (f16)(v.x * r * wv4.x);
    ob.h[1] = (f16)(v.y * r * wv4.y);
    ob.h[2] = (f16)(v.z * r * wv4.z);
    ob.h[3] = (f16)(v.w * r * wv4.w);
    ((uint2*)(o + (size_t)row * DMODEL))[tid] = ob.u;
}

// ---------------- V transpose ----------------
__global__ __launch_bounds__(256) void tv_k(const ushort_t* __restrict__ vb,
                                            ushort_t* __restrict__ vt) {
    int h = blockIdx.y, t0 = blockIdx.x * 64;
    __shared__ ushort_t T[64][76];
    int tid = threadIdx.x;
#pragma unroll
    for (int it = 0; it < 2; it++) {
        int a = tid + it * 256;
        int t = a >> 3, c8 = (a & 7) * 8;
        HF8 v;
        v.u4 = *(const uint4*)(vb + (size_t)(t0 + t) * DMODEL + h * 64 + c8);
#pragma unroll
        for (int j = 0; j < 8; j++) T[c8 + j][t] = v.s[j];
    }
    __syncthreads();
#pragma unroll
    for (int it = 0; it < 2; it++) {
        int a = tid + it * 256;
        int d = a >> 3, c8 = (a & 7) * 8;
        HF8 o;
#pragma unroll
        for (int j = 0; j < 8; j++) o.s[j] = T[d][c8 + j];
        *(uint4*)(vt + ((size_t)h * 64 + d) * SEQ + t0 + c8) = o.u4;
    }
}

// ---------------- weight transpose+convert: f32[K][N] -> f16[N][K] ----------------
__global__ __launch_bounds__(256) void transconv_k(const float* __restrict__ in,
                                                   f16* __restrict__ out,
                                                   int K, int N) {
    __shared__ f16 T[64][72];
    int k0 = blockIdx.y * 64, n0 = blockIdx.x * 64;
    int tid = threadIdx.x;
    int r = tid >> 4, c4 = (tid & 15) * 4;
#pragma unroll
    for (int i = 0; i < 4; i++) {
        float4 v = *(const float4*)(in + (size_t)(k0 + r + i * 16) * N + n0 + c4);
        T[c4 + 0][r + i * 16] = (f16)v.x;
        T[c4 + 1][r + i * 16] = (f16)v.y;
        T[c4 + 2][r + i * 16] = (f16)v.z;
        T[c4 + 3][r + i * 16] = (f16)v.w;
    }
    __syncthreads();
    int n = tid >> 2, kk = (tid & 3) * 16;
    uint4* dst = (uint4*)(out + (size_t)(n0 + n) * K + k0 + kk);
    dst[0] = *(const uint4*)&T[n][kk];
    dst[1] = *(const uint4*)&T[n][kk + 8];
}

// ---------------- 3-way weight transpose (QKV) via blockIdx.z ----------------
__global__ __launch_bounds__(256) void transconv3_k(const float* __restrict__ w0,
                                                    const float* __restrict__ w1p,
                                                    const float* __restrict__ w2p,
                                                    f16* __restrict__ out) {
    const int K = DMODEL, N = DMODEL;
    const float* in = (blockIdx.z == 0) ? w0 : (blockIdx.z == 1) ? w1p : w2p;
    f16* o = out + (size_t)blockIdx.z * DMODEL * DMODEL;
    __shared__ f16 T[64][72];
    int k0 = blockIdx.y * 64, n0 = blockIdx.x * 64;
    int tid = threadIdx.x;
    int r = tid >> 4, c4 = (tid & 15) * 4;
#pragma unroll
    for (int i = 0; i < 4; i++) {
        float4 v = *(const float4*)(in + (size_t)(k0 + r + i * 16) * N + n0 + c4);
        T[c4 + 0][r + i * 16] = (f16)v.x;
        T[c4 + 1][r + i * 16] = (f16)v.y;
        T[c4 + 2][r + i * 16] = (f16)v.z;
        T[c4 + 3][r + i * 16] = (f16)v.w;
    }
    __syncthreads();
    int n = tid >> 2, kk = (tid & 3) * 16;
    uint4* dst = (uint4*)(o + (size_t)(n0 + n) * K + k0 + kk);
    dst[0] = *(const uint4*)&T[n][kk];
    dst[1] = *(const uint4*)&T[n][kk + 8];
}

// ---------------- w1/w3 transpose+convert, row-interleaved ----------------
__global__ __launch_bounds__(256) void transconv2_k(const float* __restrict__ w1,
                                                    const float* __restrict__ w3,
                                                    f16* __restrict__ out,
                                                    int K, int N) {
    __shared__ f16 T[64][72];
    int k0 = blockIdx.y * 64, n0 = blockIdx.x * 64;
    int tid = threadIdx.x;
    int r = tid >> 4, c4 = (tid & 15) * 4;
    int n = tid >> 2, kk = (tid & 3) * 16;
#pragma unroll
    for (int half = 0; half < 2; half++) {
        const float* in = half ? w3 : w1;
#pragma unroll
        for (int i = 0; i < 4; i++) {
            float4 v = *(const float4*)(in + (size_t)(k0 + r + i * 16) * N + n0 + c4);
            T[c4 + 0][r + i * 16] = (f16)v.x;
            T[c4 + 1][r + i * 16] = (f16)v.y;
            T[c4 + 2][r + i * 16] = (f16)v.z;
            T[c4 + 3][r + i * 16] = (f16)v.w;
        }
        __syncthreads();
        int gc = n0 + n;
        int rp = (gc >> 4) * 32 + (gc & 15) + half * 16;
        uint4* dst = (uint4*)(out + (size_t)rp * K + k0 + kk);
        dst[0] = *(const uint4*)&T[n][kk];
        dst[1] = *(const uint4*)&T[n][kk + 8];
        __syncthreads();
    }
}

// ---------------- f16 MFMA GEMM 128x128 (TN), BK=64, XOR-swizzled LDS, XCD-swizzled ----------------
// mode 0: f32 out (+add). mode 1: f16 out. mode 4: w1w3-interleaved silu-mul.
__global__ __launch_bounds__(256) void gemm128_k(const f16* __restrict__ A,
                                                 const f16* __restrict__ Bt,
                                                 const float* __restrict__ add,
                                                 void* __restrict__ Cout,
                                                 int M, int N, int K, int mode) {
    __shared__ f16 Al[128 * 64];
    __shared__ f16 Bl[128 * 64];
    int tid = threadIdx.x;
    int lane = tid & 63, wave = tid >> 6;
    int gx = gridDim.x, gy = gridDim.y;
    int nwg = gx * gy;
    int bx = blockIdx.x, by = blockIdx.y;
    if ((nwg & 7) == 0) {
        int flat = by * gx + bx;
        int cpx = nwg >> 3;
        int l = (flat & 7) * cpx + (flat >> 3);
        bx = l / gy;
        by = l % gy;
    }
    int brow = by * 128, bcol = bx * 128;
    int wr = (wave >> 1) * 64, wc = (wave & 1) * 64;
    f32x4 acc[4][4];
#pragma unroll
    for (int m = 0; m < 4; m++)
#pragma unroll
        for (int n = 0; n < 4; n++) acc[m][n] = (f32x4){0.f, 0.f, 0.f, 0.f};

    int srow = tid >> 3;
    int scol = (((tid & 7) ^ (srow & 7)) * 8);
    const f16* Ag = A + (size_t)(brow + srow) * K + scol;
    const f16* Bg = Bt + (size_t)(bcol + srow) * K + scol;
    f16* Ald = &Al[wave * 512];
    f16* Bld = &Bl[wave * 512];
    size_t rstep32 = (size_t)32 * K;

    for (int k0 = 0; k0 < K; k0 += 64) {
#pragma unroll
        for (int i = 0; i < 4; i++) {
            gl_lds16(Ag + i * rstep32 + k0, Ald + i * 2048);
            gl_lds16(Bg + i * rstep32 + k0, Bld + i * 2048);
        }
        __syncthreads();
#pragma unroll
        for (int ks = 0; ks < 2; ks++) {
            f16x8 af[4], bfr[4];
            int gbase = ks * 4 + (lane >> 4);
#pragma unroll
            for (int m = 0; m < 4; m++) {
                int r = wr + m * 16 + (lane & 15);
                af[m] = *(const f16x8*)&Al[r * 64 + ((gbase ^ (r & 7)) * 8)];
            }
#pragma unroll
            for (int n = 0; n < 4; n++) {
                int r = wc + n * 16 + (lane & 15);
                bfr[n] = *(const f16x8*)&Bl[r * 64 + ((gbase ^ (r & 7)) * 8)];
            }
#pragma unroll
            for (int m = 0; m < 4; m++)
#pragma unroll
                for (int n = 0; n < 4; n++)
                    acc[m][n] = __builtin_amdgcn_mfma_f32_16x16x32_f16(af[m], bfr[n], acc[m][n], 0, 0, 0);
        }
        __syncthreads();
    }
    int crow0 = brow + wr + (lane >> 4) * 4;
    int ccol = bcol + wc + (lane & 15);
#pragma unroll
    for (int m = 0; m < 4; m++)
#pragma unroll
        for (int j = 0; j < 4; j++) {
            int row = crow0 + m * 16 + j;
            if (mode == 4) {
#pragma unroll
                for (int n = 0; n < 4; n += 2) {
                    int c = ccol + n * 16;
                    int colOut = (c >> 5) * 16 + (c & 15);
                    float v1 = acc[m][n][j];
                    float v3 = acc[m][n + 1][j];
                    ((f16*)Cout)[(size_t)row * (N / 2) + colOut] =
                        (f16)(v1 * sigm(v1) * v3);
                }
            } else {
#pragma unroll
                for (int n = 0; n < 4; n++) {
                    int col = ccol + n * 16;
                    float v = acc[m][n][j];
                    if (mode == 0) {
                        if (add) v += add[(size_t)row * N + col];
                        ((float*)Cout)[(size_t)row * N + col] = v;
                    } else {
                        ((f16*)Cout)[(size_t)row * N + col] = (f16)v;
                    }
                }
            }
        }
}

// ---------------- f16 MFMA GEMM 64x64 (TN), BK=64, XOR-swizzled LDS, XCD-swizzled ----------------
// mode 0: f32 out (+add). mode 1: f16. mode 2: qkv split (Cout=q, p2=k, p3=v).
__global__ __launch_bounds__(256) void gemm64_k(const f16* __restrict__ A,
                                                const f16* __restrict__ Bt,
                                                const float* __restrict__ add,
                                                void* __restrict__ Cout,
                                                int M, int N, int K, int mode,
                                                f16* __restrict__ p2,
                                                f16* __restrict__ p3) {
    __shared__ f16 Al[64 * 64];
    __shared__ f16 Bl[64 * 64];
    int tid = threadIdx.x;
    int lane = tid & 63, wave = tid >> 6;
    int gx = gridDim.x, gy = gridDim.y;
    int nwg = gx * gy;
    int bx = blockIdx.x, by = blockIdx.y;
    if ((nwg & 7) == 0) {
        int flat = by * gx + bx;
        int cpx = nwg >> 3;
        int l = (flat & 7) * cpx + (flat >> 3);
        bx = l / gy;
        by = l % gy;
    }
    int brow = by * 64, bcol = bx * 64;
    int wr = (wave >> 1) * 32, wc = (wave & 1) * 32;
    f32x4 acc[2][2];
#pragma unroll
    for (int m = 0; m < 2; m++)
#pragma unroll
        for (int n = 0; n < 2; n++) acc[m][n] = (f32x4){0.f, 0.f, 0.f, 0.f};

    int srow = tid >> 3;
    int scol = (((tid & 7) ^ (srow & 7)) * 8);
    const f16* Ag = A + (size_t)(brow + srow) * K + scol;
    const f16* Bg = Bt + (size_t)(bcol + srow) * K + scol;
    f16* Ald = &Al[wave * 512];
    f16* Bld = &Bl[wave * 512];
    size_t rstep32 = (size_t)32 * K;

    for (int k0 = 0; k0 < K; k0 += 64) {
        gl_lds16(Ag + k0, Ald);
        gl_lds16(Ag + rstep32 + k0, Ald + 2048);
        gl_lds16(Bg + k0, Bld);
        gl_lds16(Bg + rstep32 + k0, Bld + 2048);
        __syncthreads();
#pragma unroll
        for (int ks = 0; ks < 2; ks++) {
            f16x8 af[2], bfr[2];
            int gbase = ks * 4 + (lane >> 4);
#pragma unroll
            for (int m = 0; m < 2; m++) {
                int r = wr + m * 16 + (lane & 15);
                af[m] = *(const f16x8*)&Al[r * 64 + ((gbase ^ (r & 7)) * 8)];
            }
#pragma unroll
            for (int n = 0; n < 2; n++) {
                int r = wc + n * 16 + (lane & 15);
                bfr[n] = *(const f16x8*)&Bl[r * 64 + ((gbase ^ (r & 7)) * 8)];
            }
#pragma unroll
            for (int m = 0; m < 2; m++)
#pragma unroll
                for (int n = 0; n < 2; n++)
                    acc[m][n] = __builtin_amdgcn_mfma_f32_16x16x32_f16(af[m], bfr[n], acc[m][n], 0, 0, 0);
        }
        __syncthreads();
    }
    int crow0 = brow + wr + (lane >> 4) * 4;
    int ccol = bcol + wc + (lane & 15);
#pragma unroll
    for (int m = 0; m < 2; m++)
#pragma unroll
        for (int j = 0; j < 4; j++) {
            int row = crow0 + m * 16 + j;
#pragma unroll
            for (int n = 0; n < 2; n++) {
                int col = ccol + n * 16;
                float v = acc[m][n][j];
                if (mode == 0) {
                    if (add) v += add[(size_t)row * N + col];
                    ((float*)Cout)[(size_t)row * N + col] = v;
                } else if (mode == 1) {
                    ((f16*)Cout)[(size_t)row * N + col] = (f16)v;
                } else {
                    size_t o = (size_t)row * DMODEL;
                    if (col < DMODEL) ((f16*)Cout)[o + col] = (f16)v;
                    else if (col < 2 * DMODEL) p2[o + col - DMODEL] = (f16)v;
                    else p3[o + col - 2 * DMODEL] = (f16)v;
                }
            }
        }
}

// ---------------- MFMA scores, 128x128 tile ----------------
__global__ __launch_bounds__(256) void scoresm_k(const f16* __restrict__ qf,
                                                 const f16* __restrict__ kf,
                                                 f16* __restrict__ sc, int cb) {
    int h = blockIdx.z;
    int il0 = blockIdx.y * 128;
    int j0 = blockIdx.x * 128;
    __shared__ f16 Qf[128][72];
    __shared__ f16 Kf[128][72];
    int tid = threadIdx.x;
#pragma unroll
    for (int i = 0; i < 4; i++) {
        int row = i * 32 + (tid >> 3);
        int c8 = (tid & 7) * 8;
        *(uint4*)&Qf[row][c8] =
            *(const uint4*)(qf + (size_t)(cb + il0 + row) * DMODEL + h * 64 + c8);
        *(uint4*)&Kf[row][c8] =
            *(const uint4*)(kf + (size_t)(j0 + row) * DMODEL + h * 64 + c8);
    }
    __syncthreads();
    int lane = tid & 63, wave = tid >> 6;
    int wr = (wave >> 1) * 64, wc = (wave & 1) * 64;
    f32x4 acc[4][4];
#pragma unroll
    for (int m = 0; m < 4; m++)
#pragma unroll
        for (int n = 0; n < 4; n++) acc[m][n] = (f32x4){0.f, 0.f, 0.f, 0.f};
#pragma unroll
    for (int ks = 0; ks < 2; ks++) {
        int kof = ks * 32 + (lane >> 4) * 8;
        f16x8 aQ[4], bK[4];
#pragma unroll
        for (int m = 0; m < 4; m++)
            aQ[m] = *(const f16x8*)&Qf[wr + m * 16 + (lane & 15)][kof];
#pragma unroll
        for (int n = 0; n < 4; n++)
            bK[n] = *(const f16x8*)&Kf[wc + n * 16 + (lane & 15)][kof];
#pragma unroll
        for (int m = 0; m < 4; m++)
#pragma unroll
            for (int n = 0; n < 4; n++)
                acc[m][n] = __builtin_amdgcn_mfma_f32_16x16x32_f16(aQ[m], bK[n], acc[m][n], 0, 0, 0);
    }
#pragma unroll
    for (int m = 0; m < 4; m++)
#pragma unroll
        for (int j = 0; j < 4; j++) {
            int il = il0 + wr + m * 16 + (lane >> 4) * 4 + j;
#pragma unroll
            for (int n = 0; n < 4; n++) {
                int jj = j0 + wc + n * 16 + (lane & 15);
                sc[((size_t)h * CHUNK + il) * SEQ + jj] = (f16)(acc[m][n][j] * 0.125f);
            }
        }
}

// ---------------- logits_int -> f16 ----------------
__global__ __launch_bounds__(256) void copelogits_k(const f16* __restrict__ qf,
                                                    const float* __restrict__ pe,
                                                    f16* __restrict__ li) {
    int s1 = blockIdx.x;
    int tid = threadIdx.x;
    __shared__ float PE[DHEAD * NPOSE];
    __shared__ float QR[DMODEL];
    for (int i = tid; i < DHEAD * NPOSE; i += 256) PE[i] = pe[i];
    for (int i = tid; i < DMODEL; i += 256) QR[i] = (float)qf[(size_t)s1 * DMODEL + i];
    __syncthreads();
#pragma unroll
    for (int j = 0; j < 8; j++) {
        int o = j * 256 + tid;
        int h = o >> 7, n = o & 127;
        const float* qhp = &QR[h * DHEAD];
        float acc = 0.0f;
#pragma unroll 8
        for (int d = 0; d < DHEAD; d++) acc += qhp[d] * PE[d * NPOSE + n];
        li[(size_t)s1 * (NH * NPOSE) + o] = (f16)acc;
    }
}

// ---------------- fused CoPE: ILP scan + bias + f16 MFMA MLP + softmax -> P ----------------
#define CSTR 2052
__global__ __launch_bounds__(1024, 1) void cope_k(f16* __restrict__ sc,
                                                  const f16* __restrict__ li,
                                                  const float* __restrict__ w1,
                                                  const float* __restrict__ b1,
                                                  const float* __restrict__ w2,
                                                  const float* __restrict__ b2,
                                                  int cb) {
    __shared__ f16 C[32 * CSTR];
    __shared__ uint_t Lif2[NH * 130];
    __shared__ f16 HMB[16][16 * 36];
    int r = blockIdx.x;
    int tid = threadIdx.x;
    int lane = tid & 63, wv = tid >> 6;

    const f16* srow = sc + ((size_t)wv * CHUNK + r) * SEQ;
    HF8 rv[4];
#pragma unroll
    for (int c = 0; c < 4; c++) rv[c].u4 = *(const uint4*)&srow[c * 512 + lane * 8];

    {
        const f16* lh = li + (size_t)(cb + r) * (NH * NPOSE) + wv * NPOSE;
#pragma unroll
        for (int e = 0; e < 2; e++) {
            int n = lane + e * 64;
            U1H2 pk;
            pk.h[0] = lh[n];
            pk.h[1] = lh[(n < NPOSE - 1) ? n + 1 : NPOSE - 1];
            Lif2[wv * 130 + n] = pk.u;
        }
    }

    {
        f16* crow = &C[wv * CSTR];
        f16* brow = &C[(16 + wv) * CSTR];
        const uint_t* lrow = &Lif2[wv * 130];
        float g[4][8];
        float S[4];
#pragma unroll
        for (int c = 0; c < 4; c++) {
            HF8 sv = rv[c];
            float s = 0.0f;
#pragma unroll
            for (int e = 0; e < 8; e++) {
                g[c][e] = sigm((float)sv.h[e]);
                s += g[c][e];
            }
            S[c] = s;
        }
#pragma unroll
        for (int dd = 1; dd < 64; dd <<= 1) {
#pragma unroll
            for (int c = 0; c < 4; c++) {
                float o = __shfl_down(S[c], dd, 64);
                S[c] = (lane + dd < 64) ? S[c] + o : S[c];
            }
        }
        float tot[4];
#pragma unroll
        for (int c = 0; c < 4; c++) tot[c] = __shfl(S[c], 0, 64);
        float carry[4];
        carry[3] = 0.0f;
        carry[2] = tot[3];
        carry[1] = tot[3] + tot[2];
        carry[0] = carry[1] + tot[1];
#pragma unroll
        for (int c = 0; c < 4; c++) {
            float p = S[c] + carry[c];
            HF8 bo;
#pragma unroll
            for (int e = 0; e < 8; e++) {
                float pos = fminf(p, 127.0f);
                int fl = (int)pos;
                float fr = pos - (float)fl;
                U1H2 lv;
                lv.u = lrow[fl];
                float lf = (float)lv.h[0];
                bo.h[e] = (f16)(lf + ((float)lv.h[1] - lf) * fr);
                p -= g[c][e];
            }
            int t = c * 512 + lane * 8;
            *(uint4*)&crow[t] = rv[c].u4;
            *(uint4*)&brow[t] = bo.u4;
        }
    }
    __syncthreads();

    int fkg = lane >> 4;
    int fc = lane & 15;
    HF8 w1f[2], w2f;
    float b1v[2], b2v;
#pragma unroll
    for (int half = 0; half < 2; half++) {
#pragma unroll
        for (int j = 0; j < 8; j++)
            w1f[half].h[j] = (f16)w1[(fkg * 8 + j) * MLPWID + half * 16 + fc];
        b1v[half] = b1[half * 16 + fc];
    }
#pragma unroll
    for (int j = 0; j < 8; j++) w2f.h[j] = (f16)w2[(fkg * 8 + j) * NH + fc];
    b2v = b2[fc];

    f16* hmb = HMB[wv];
#pragma unroll 2
    for (int tt = wv; tt < SEQ / 16; tt += 16) {
        int t0 = tt * 16;
        HF8 af;
#pragma unroll
        for (int j = 0; j < 8; j++) af.h[j] = C[(fkg * 8 + j) * CSTR + t0 + fc];
        f32x4 acc0 = (f32x4){b1v[0], b1v[0], b1v[0], b1v[0]};
        f32x4 acc1 = (f32x4){b1v[1], b1v[1], b1v[1], b1v[1]};
        acc0 = __builtin_amdgcn_mfma_f32_16x16x32_f16(af.v, w1f[0].v, acc0, 0, 0, 0);
        acc1 = __builtin_amdgcn_mfma_f32_16x16x32_f16(af.v, w1f[1].v, acc1, 0, 0, 0);
#pragma unroll
        for (int j2 = 0; j2 < 4; j2++) {
            int p = fkg * 4 + j2;
            float h0 = acc0[j2]; h0 = h0 * sigm(h0);
            float h1 = acc1[j2]; h1 = h1 * sigm(h1);
            hmb[p * 36 + fc] = (f16)h0;
            hmb[p * 36 + 16 + fc] = (f16)h1;
        }
        HF8 hf;
        hf.u2[0] = *(const uint2*)&hmb[fc * 36 + fkg * 8];
        hf.u2[1] = *(const uint2*)&hmb[fc * 36 + fkg * 8 + 4];
        f32x4 acc2 = (f32x4){b2v, b2v, b2v, b2v};
        acc2 = __builtin_amdgcn_mfma_f32_16x16x32_f16(hf.v, w2f.v, acc2, 0, 0, 0);
#pragma unroll
        for (int j2 = 0; j2 < 4; j2 += 2) {
            uint_t* pp = (uint_t*)&C[fc * CSTR + t0 + fkg * 4 + j2];
            U1H2 old, neu;
            old.u = *pp;
            neu.h[0] = (f16)((float)old.h[0] + acc2[j2]);
            neu.h[1] = (f16)((float)old.h[1] + acc2[j2 + 1]);
            *pp = neu.u;
        }
    }
    __syncthreads();

    {
        const f16* row = &C[wv * CSTR];
        float vals[32];
        float m = -1e30f;
#pragma unroll
        for (int c = 0; c < 4; c++) {
            HF8 sv;
            sv.u4 = *(const uint4*)&row[c * 512 + lane * 8];
#pragma unroll
            for (int e = 0; e < 8; e++) {
                vals[c * 8 + e] = (float)sv.h[e];
                m = fmaxf(m, vals[c * 8 + e]);
            }
        }
#pragma unroll
        for (int d = 1; d < 64; d <<= 1) m = fmaxf(m, __shfl_xor(m, d, 64));
        float s = 0.0f;
#pragma unroll
        for (int c = 0; c < 32; c++) {
            vals[c] = __expf(vals[c] - m);
            s += vals[c];
        }
#pragma unroll
        for (int d = 1; d < 64; d <<= 1) s += __shfl_xor(s, d, 64);
        float ri = __builtin_amdgcn_rcpf(s);
        f16* dst = sc + ((size_t)wv * CHUNK + r) * SEQ;
#pragma unroll
        for (int c = 0; c < 4; c++) {
            HF8 po;
#pragma unroll
            for (int e = 0; e < 8; e++) po.h[e] = (f16)(vals[c * 8 + e] * ri);
            *(uint4*)&dst[c * 512 + lane * 8] = po.u4;
        }
    }
}

// ---------------- f16 MFMA PV, KT=128 staging ----------------
__global__ __launch_bounds__(256) void pvm_k(const f16* __restrict__ scP,
                                             const ushort_t* __restrict__ vt,
                                             f16* __restrict__ aob, int cb) {
    int h = blockIdx.y;
    int s0 = blockIdx.x * 32;
    __shared__ f16 P[32][136];
    __shared__ f16 Vt[64][136];
    int tid = threadIdx.x;
    int lane = tid & 63, wave = tid >> 6;
    int wr = (wave >> 1) * 16, wc = (wave & 1) * 32;
    f32x4 acc[2];
    acc[0] = (f32x4){0.f, 0.f, 0.f, 0.f};
    acc[1] = (f32x4){0.f, 0.f, 0.f, 0.f};
    int pr = tid >> 3, pc = (tid & 7) * 16;   // P: 32 rows x 128, 16 f16/thread
    int vr = tid >> 2, vc = (tid & 3) * 32;   // Vt: 64 rows x 128, 32 f16/thread
    for (int t0 = 0; t0 < SEQ; t0 += 128) {
        {
            const f16* pp = scP + ((size_t)h * CHUNK + s0 + pr) * SEQ + t0 + pc;
            *(uint4*)&P[pr][pc] = *(const uint4*)pp;
            *(uint4*)&P[pr][pc + 8] = *(const uint4*)(pp + 8);
            const ushort_t* vp = vt + ((size_t)h * 64 + vr) * SEQ + t0 + vc;
            *(uint4*)&Vt[vr][vc] = *(const uint4*)vp;
            *(uint4*)&Vt[vr][vc + 8] = *(const uint4*)(vp + 8);
            *(uint4*)&Vt[vr][vc + 16] = *(const uint4*)(vp + 16);
            *(uint4*)&Vt[vr][vc + 24] = *(const uint4*)(vp + 24);
        }
        __syncthreads();
#pragma unroll
        for (int ks = 0; ks < 4; ks++) {
            int kof = ks * 32 + (lane >> 4) * 8;
            f16x8 pa = *(const f16x8*)&P[wr + (lane & 15)][kof];
#pragma unroll
            for (int n = 0; n < 2; n++) {
                f16x8 vb = *(const f16x8*)&Vt[wc + n * 16 + (lane & 15)][kof];
                acc[n] = __builtin_amdgcn_mfma_f32_16x16x32_f16(pa, vb, acc[n], 0, 0, 0);
            }
        }
        __syncthreads();
    }
#pragma unroll
    for (int j = 0; j < 4; j++) {
        int s = cb + s0 + wr + (lane >> 4) * 4 + j;
#pragma unroll
        for (int n = 0; n < 2; n++) {
            int d = h * 64 + wc + n * 16 + (lane & 15);
            aob[(size_t)s * DMODEL + d] = (f16)acc[n][j];
        }
    }
}

extern "C" void kernel_launch(void* const* d_in, const int* in_sizes, int n_in,
                              void* d_out, int out_size, void* d_ws, size_t ws_size,
                              hipStream_t stream) {
    const float* x = (const float*)d_in[0];
    const float* wq = (const float*)d_in[1];
    const float* wk = (const float*)d_in[2];
    const float* wv = (const float*)d_in[3];
    const float* wo = (const float*)d_in[4];
    const float* pos_emb = (const float*)d_in[5];
    const float* mlp_w1 = (const float*)d_in[6];
    const float* mlp_b1 = (const float*)d_in[7];
    const float* mlp_w2 = (const float*)d_in[8];
    const float* mlp_b2 = (const float*)d_in[9];
    const float* ffn_w1 = (const float*)d_in[10];
    const float* ffn_w2 = (const float*)d_in[11];
    const float* ffn_w3 = (const float*)d_in[12];
    const float* attn_norm_w = (const float*)d_in[13];
    const float* ffn_norm_w = (const float*)d_in[14];
    float* out = (float*)d_out;

    char* ws = (char*)d_ws;
    const size_t MB = 1024 * 1024;
    f16* nxb = (f16*)(ws + 0);               // 0-4
    f16* qf = (f16*)(ws + 4 * MB);           // 4-8   (phase C: nxb2)
    f16* kf = (f16*)(ws + 8 * MB);           // 8-12  (phase C: g1b 8-24)
    f16* vb = (f16*)(ws + 12 * MB);          // 12-16
    f16* vt = (f16*)(ws + 16 * MB);          // 16-20
    f16* li = (f16*)(ws + 20 * MB);          // 20-28
    f16* aob = (f16*)(ws + 28 * MB);         // 28-32
    float* x1 = (float*)(ws + 32 * MB);      // 32-40
    f16* wqkvt = (f16*)(ws + 40 * MB);       // 40-46 (phase 1)
    f16* sc = (f16*)(ws + 40 * MB);          // 40-104 (phase 2, CHUNK=1024)
    f16* wot = (f16*)(ws + 40 * MB);         // 40-42 (phase B)
    f16* w13t = (f16*)(ws + 40 * MB);        // 40-56 (phase C, interleaved)
    f16* w2t = (f16*)(ws + 56 * MB);         // 56-64
    f16* nxb2 = (f16*)(ws + 4 * MB);
    f16* g1b = (f16*)(ws + 8 * MB);          // 8-24

    // ---- phase 1: norm + fused QKV (64-tile, 1536 blocks) ----
    transconv3_k<<<dim3(DMODEL / 64, DMODEL / 64, 3), 256, 0, stream>>>(wq, wk, wv, wqkvt);
    rmsnormf_k<<<SEQ, 256, 0, stream>>>(x, attn_norm_w, nxb);
    gemm64_k<<<dim3(3 * DMODEL / 64, SEQ / 64), 256, 0, stream>>>(
        nxb, wqkvt, nullptr, qf, SEQ, 3 * DMODEL, DMODEL, 2, kf, vb);
    copelogits_k<<<SEQ, 256, 0, stream>>>(qf, pos_emb, li);
    tv_k<<<dim3(SEQ / 64, NH), 256, 0, stream>>>((const ushort_t*)vb, (ushort_t*)vt);

    // ---- phase 2: attention chunks ----
    for (int ch = 0; ch < NCH; ch++) {
        int cb = ch * CHUNK;
        scoresm_k<<<dim3(SEQ / 128, CHUNK / 128, NH), 256, 0, stream>>>(qf, kf, sc, cb);
        cope_k<<<CHUNK, 1024, 0, stream>>>(sc, li, mlp_w1, mlp_b1, mlp_w2, mlp_b2, cb);
        pvm_k<<<dim3(CHUNK / 32, NH), 256, 0, stream>>>(sc, (const ushort_t*)vt, aob, cb);
    }

    // ---- phase B: out @ wo + x (64-tile, 512 blocks) ----
    transconv_k<<<dim3(DMODEL / 64, DMODEL / 64), 256, 0, stream>>>(wo, wot, DMODEL, DMODEL);
    gemm64_k<<<dim3(DMODEL / 64, SEQ / 64), 256, 0, stream>>>(
        aob, wot, x, x1, SEQ, DMODEL, DMODEL, 0, nullptr, nullptr);

    // ---- phase C: FFN ----
    rmsnormf_k<<<SEQ, 256, 0, stream>>>(x1, ffn_norm_w, nxb2);
    transconv2_k<<<dim3(FFDIM / 64, DMODEL / 64), 256, 0, stream>>>(ffn_w1, ffn_w3, w13t, DMODEL, FFDIM);
    transconv_k<<<dim3(DMODEL / 64, FFDIM / 64), 256, 0, stream>>>(ffn_w2, w2t, FFDIM, DMODEL);
    gemm128_k<<<dim3(2 * FFDIM / 128, SEQ / 128), 256, 0, stream>>>(
        nxb2, w13t, nullptr, g1b, SEQ, 2 * FFDIM, DMODEL, 4);
    gemm64_k<<<dim3(DMODEL / 64, SEQ / 64), 256, 0, stream>>>(
        g1b, w2t, x1, out, SEQ, DMODEL, FFDIM, 0, nullptr, nullptr);
}